// Round 8
// baseline (2909.045 us; speedup 1.0000x reference)
//
#include <hip/hip_runtime.h>

#define NBUS 131072
#define NGEN 32768
#define NALL (NBUS + NGEN)
#define NEBB 2097152
#define NEGB 65536
#define NEBG 65536
#define NEBUS (NEBB + NEGB)   // merged bus-dest CSR (bb + gb)
#define NTILE (NALL / 64)     // 2560
#define NTILE_BUS (NBUS / 64) // 2048

typedef float f32x2 __attribute__((ext_vector_type(2)));
typedef unsigned short u16;

__device__ inline f32x2 bf2x2(unsigned v) {  // unpack 2 bf16 (packed u32) -> 2 f32
  f32x2 r;
  r.x = __builtin_bit_cast(float, v << 16);
  r.y = __builtin_bit_cast(float, v & 0xFFFF0000u);
  return r;
}
__device__ inline u16 f2bf(float f) {  // round-to-nearest-even
  unsigned u = __builtin_bit_cast(unsigned, f);
  unsigned r = u + 0x7FFFu + ((u >> 16) & 1u);
  return (u16)(r >> 16);
}
__device__ inline unsigned pack2bf(float a, float b) {
  return (unsigned)f2bf(a) | ((unsigned)f2bf(b) << 16);
}

// ---------------- CSR build: XCD-sliced hist (one dispatch, 3 edge lists) ----------------
// Block's slice g = blockIdx&7; only counts dests in slice g -> count-line atomics stay
// in one XCD's L2 (no cross-XCD line ping-pong).
__global__ void __launch_bounds__(256) k_hist_sl(const int* __restrict__ bbDst,
                                                 const int* __restrict__ gbDst,
                                                 const int* __restrict__ bgDst,
                                                 int* __restrict__ busCnt,
                                                 int* __restrict__ bgCnt) {
  const int g = blockIdx.x & 7;
  const int blk = blockIdx.x >> 3;
  const int nblk = gridDim.x >> 3;
  const int start = blk * 256 + threadIdx.x;
  const int stride = nblk * 256;
  for (int i = start; i < NEBB; i += stride) {
    int d = __builtin_nontemporal_load(&bbDst[i]);
    if ((d >> 14) == g) atomicAdd(&busCnt[d], 1);
  }
  for (int i = start; i < NEGB; i += stride) {
    int d = __builtin_nontemporal_load(&gbDst[i]);
    if ((d >> 14) == g) atomicAdd(&busCnt[d], 1);
  }
  for (int i = start; i < NEBG; i += stride) {
    int d = __builtin_nontemporal_load(&bgDst[i]);
    if ((d >> 12) == g) atomicAdd(&bgCnt[d], 1);
  }
}

__global__ void k_scan1(const int* __restrict__ in, int* __restrict__ out,
                        int* __restrict__ bsums, int n) {
  __shared__ int sh[256];
  int t = threadIdx.x;
  int base = blockIdx.x * 1024 + t * 4;
  int v0 = (base + 0 < n) ? in[base + 0] : 0;
  int v1 = (base + 1 < n) ? in[base + 1] : 0;
  int v2 = (base + 2 < n) ? in[base + 2] : 0;
  int v3 = (base + 3 < n) ? in[base + 3] : 0;
  int t0 = v0, t1 = t0 + v1, t2 = t1 + v2, t3 = t2 + v3;
  sh[t] = t3;
  __syncthreads();
  for (int off = 1; off < 256; off <<= 1) {
    int x = (t >= off) ? sh[t - off] : 0;
    __syncthreads();
    sh[t] += x;
    __syncthreads();
  }
  int excl = (t > 0) ? sh[t - 1] : 0;
  if (base + 0 < n) out[base + 0] = excl;
  if (base + 1 < n) out[base + 1] = excl + t0;
  if (base + 2 < n) out[base + 2] = excl + t1;
  if (base + 3 < n) out[base + 3] = excl + t2;
  if (t == 255) bsums[blockIdx.x] = sh[255];
}

__global__ void k_scan2(int* __restrict__ bsums, int nb) {
  __shared__ int sh[256];
  int t = threadIdx.x;
  int v = (t < nb) ? bsums[t] : 0;
  sh[t] = v;
  __syncthreads();
  for (int off = 1; off < 256; off <<= 1) {
    int x = (t >= off) ? sh[t - off] : 0;
    __syncthreads();
    sh[t] += x;
    __syncthreads();
  }
  int excl = (t > 0) ? sh[t - 1] : 0;
  if (t < nb) bsums[t] = excl;
}

__global__ void k_scan3(int* __restrict__ off, int* __restrict__ cur,
                        const int* __restrict__ bsums, int n, int E) {
  int stride = gridDim.x * blockDim.x;
  for (int i = blockIdx.x * blockDim.x + threadIdx.x; i < n; i += stride) {
    int o = off[i] + bsums[i >> 10];
    off[i] = o;
    cur[i] = o;
  }
  if (blockIdx.x == 0 && threadIdx.x == 0) off[n] = E;
}

// ---------------- CSR fill: XCD-sliced (one dispatch, 3 edge lists) ----------------
// Slice-g's srt region is contiguous (CSR offsets monotone) and written only by
// XCD-g blocks -> full-line, single-XCD dirty lines (fixes the 136 MB write blowup).
__global__ void __launch_bounds__(256) k_fill_sl(const int* __restrict__ bbSrc,
                                                 const int* __restrict__ bbDst,
                                                 const int* __restrict__ gbSrc,
                                                 const int* __restrict__ gbDst,
                                                 const int* __restrict__ bgSrc,
                                                 const int* __restrict__ bgDst,
                                                 int* __restrict__ busCur,
                                                 int* __restrict__ bgCur,
                                                 int* __restrict__ busSrt,
                                                 int* __restrict__ bgSrt) {
  const int g = blockIdx.x & 7;
  const int tid = threadIdx.x;
  if (blockIdx.x < 2048) {          // bus-bus edges
    const int blk = blockIdx.x >> 3;
    const int stride = 256 * 256;
    for (int i = blk * 256 + tid; i < NEBB; i += stride) {
      int d = __builtin_nontemporal_load(&bbDst[i]);
      if ((d >> 14) == g) {
        int p = atomicAdd(&busCur[d], 1);
        busSrt[p] = __builtin_nontemporal_load(&bbSrc[i]);
      }
    }
  } else if (blockIdx.x < 2304) {   // gen->bus edges (src offset +NBUS)
    const int blk = (blockIdx.x - 2048) >> 3;
    const int stride = 32 * 256;
    for (int i = blk * 256 + tid; i < NEGB; i += stride) {
      int d = __builtin_nontemporal_load(&gbDst[i]);
      if ((d >> 14) == g) {
        int p = atomicAdd(&busCur[d], 1);
        busSrt[p] = __builtin_nontemporal_load(&gbSrc[i]) + NBUS;
      }
    }
  } else {                          // bus->gen edges
    const int blk = (blockIdx.x - 2304) >> 3;
    const int stride = 32 * 256;
    for (int i = blk * 256 + tid; i < NEBG; i += stride) {
      int d = __builtin_nontemporal_load(&bgDst[i]);
      if ((d >> 12) == g) {
        int p = atomicAdd(&bgCur[d], 1);
        bgSrt[p] = __builtin_nontemporal_load(&bgSrc[i]);
      }
    }
  }
}

// ---------------- merged readin (bus+gen rows) + fused BN-stats ----------------
__global__ void __launch_bounds__(256) k_readin(const float* __restrict__ xbus,
                                                const float* __restrict__ xgen,
                                                const float* __restrict__ Wb,
                                                const float* __restrict__ bb_,
                                                const float* __restrict__ Wg,
                                                const float* __restrict__ bg_,
                                                float* __restrict__ y,
                                                float* __restrict__ stats) {
  __shared__ float WsB[2048];
  __shared__ float WsG[2048];
  __shared__ float shs[4][64];
  __shared__ float shs2[4][64];
  for (int i = threadIdx.x; i < 2048; i += 256) {
    WsB[i] = Wb[i];
    WsG[i] = Wg[i];
  }
  __syncthreads();
  int lane = threadIdx.x & 63;
  int wib = threadIdx.x >> 6;
  float bvB = bb_[lane], bvG = bg_[lane];
  int w = (blockIdx.x * blockDim.x + threadIdx.x) >> 6;
  int nw = (gridDim.x * blockDim.x) >> 6;
  float lsB = 0.f, ls2B = 0.f, lsG = 0.f, ls2G = 0.f;
  for (int g = w; g < NALL; g += nw) {
    bool isBus = g < NBUS;
    const float* xin = isBus ? xbus : xgen;
    int rl = isBus ? g : g - NBUS;
    const float* Ws = isBus ? WsB : WsG;
    float v = xin[(size_t)rl * 32 + (lane & 31)];
    float acc = isBus ? bvB : bvG;
#pragma unroll
    for (int i = 0; i < 32; i++) {
      float xi = __shfl(v, i, 64);
      acc = fmaf(xi, Ws[i * 64 + lane], acc);
    }
    y[(size_t)g * 64 + lane] = acc;
    if (isBus) {
      lsB += acc;
      ls2B = fmaf(acc, acc, ls2B);
    } else {
      lsG += acc;
      ls2G = fmaf(acc, acc, ls2G);
    }
  }
  shs[wib][lane] = lsB;
  shs2[wib][lane] = ls2B;
  __syncthreads();
  if (threadIdx.x < 64) {
    int c = threadIdx.x;
    atomicAdd(&stats[c], shs[0][c] + shs[1][c] + shs[2][c] + shs[3][c]);
  } else if (threadIdx.x < 128) {
    int c = threadIdx.x & 63;
    atomicAdd(&stats[64 + c], shs2[0][c] + shs2[1][c] + shs2[2][c] + shs2[3][c]);
  }
  __syncthreads();
  shs[wib][lane] = lsG;
  shs2[wib][lane] = ls2G;
  __syncthreads();
  if (threadIdx.x < 64) {
    int c = threadIdx.x;
    atomicAdd(&stats[128 + c], shs[0][c] + shs[1][c] + shs[2][c] + shs[3][c]);
  } else if (threadIdx.x < 128) {
    int c = threadIdx.x & 63;
    atomicAdd(&stats[192 + c], shs2[0][c] + shs2[1][c] + shs2[2][c] + shs2[3][c]);
  }
}

// ---------------- BN-finalize + normalize + lrelu + tap0, 64-row tiles ----------------
__global__ void __launch_bounds__(256) k_norm_tap0(float* __restrict__ x,
                                                   u16* __restrict__ c_sl,
                                                   const float* __restrict__ stats,
                                                   const float* __restrict__ gammaB,
                                                   const float* __restrict__ betaB,
                                                   const float* __restrict__ gammaG,
                                                   const float* __restrict__ betaG,
                                                   const float* __restrict__ tWb,
                                                   const float* __restrict__ tbb,
                                                   const float* __restrict__ tWg,
                                                   const float* __restrict__ tbg,
                                                   int tapIdx) {
  __shared__ float Ws[4096];
  int tile = blockIdx.x;
  bool isBus = tile < NTILE_BUS;
  const float* W = (isBus ? tWb : tWg) + (size_t)tapIdx * 4096;
  for (int i = threadIdx.x; i < 4096; i += 256) Ws[i] = W[i];
  int lane = threadIdx.x & 63;
  int wv = threadIdx.x >> 6;
  int so = isBus ? 0 : 128;
  float invN = isBus ? (1.0f / NBUS) : (1.0f / NGEN);
  float m = stats[so + lane] * invN;
  float m2 = stats[so + 64 + lane] * invN;
  float rs = rsqrtf(m2 - m * m + 1e-5f);
  float scale = (isBus ? gammaB : gammaG)[lane] * rs;
  float shift = (isBus ? betaB : betaG)[lane] - m * scale;
  float bv = ((isBus ? tbb : tbg) + (size_t)tapIdx * 64)[lane];
  __syncthreads();
  const int sg = lane >> 3;         // slab for this lane's channel pair
  const int scc = (lane & 7) >> 1;  // u32 slot within slab row
  unsigned* slu = (unsigned*)c_sl;
  int row0 = tile * 64 + wv * 16;
  for (int i = 0; i < 16; i++) {
    int row = row0 + i;
    size_t idx = (size_t)row * 64 + lane;
    float xv = __builtin_nontemporal_load(&x[idx]);
    float y = fmaf(xv, scale, shift);
    y = (y >= 0.f) ? y : 0.01f * y;
    float ypair = __shfl(y, lane ^ 1, 64);
    if ((lane & 1) == 0)  // even lane packs (even,odd) channels into sliced slab
      slu[((size_t)sg * NALL + row) * 4 + scc] = pack2bf(y, ypair);
    float acc = bv;
#pragma unroll
    for (int t = 0; t < 64; t++) {
      float yi = __shfl(y, t, 64);
      acc = fmaf(yi, Ws[t * 64 + lane], acc);
    }
    __builtin_nontemporal_store(xv + acc, &x[idx]);
  }
}

// ---------------- phase A: pure CSR gather, XCD-sliced slabs (L2-resident) --------------
// 16-edge srt chunks: 4 coalesced scalar loads per lane + shfl within the 4-lane group
// -> one srt-load latency covers an average row; 16 slab loads in flight per lane.
__global__ void __launch_bounds__(256) k_gather(const int* __restrict__ busOff,
                                                const int* __restrict__ busSrt,
                                                const int* __restrict__ bgOff,
                                                const int* __restrict__ bgSrt,
                                                const u16* __restrict__ src_sl,
                                                u16* __restrict__ dst_sl) {
  const int lane = threadIdx.x & 63;
  const int wv = threadIdx.x >> 6;  // wave in block (0..3)
  const int grp = lane >> 2;        // row slot (0..15)
  const int cc = lane & 3;          // u32 slot (2 channels)
  const int gb = grp << 2;          // group base lane
  const int g = blockIdx.x & 7;     // channel group -> XCD
  const int blk = blockIdx.x >> 3;
  const int nblk = gridDim.x >> 3;
  const unsigned* src32 = (const unsigned*)src_sl + (size_t)g * NALL * 4;
  unsigned* dsl = (unsigned*)dst_sl + (size_t)g * NALL * 4;
  for (int base = blk * 64; base < NALL; base += nblk * 64) {
    int row = base + wv * 16 + grp;
    int beg, end;
    const int* srt;
    if (row < NBUS) {
      beg = __builtin_nontemporal_load(&busOff[row]);
      end = __builtin_nontemporal_load(&busOff[row + 1]);
      srt = busSrt;
    } else {
      int rr = row - NBUS;
      beg = __builtin_nontemporal_load(&bgOff[rr]);
      end = __builtin_nontemporal_load(&bgOff[rr + 1]);
      srt = bgSrt;
    }
    f32x2 a0 = {0.f, 0.f}, a1 = {0.f, 0.f}, a2 = {0.f, 0.f}, a3 = {0.f, 0.f};
    int e = beg;
    for (; e + 16 <= end; e += 16) {  // 16 edges: one srt latency, 16 loads in flight
      int w0 = __builtin_nontemporal_load(&srt[e + cc]);
      int w1 = __builtin_nontemporal_load(&srt[e + 4 + cc]);
      int w2 = __builtin_nontemporal_load(&srt[e + 8 + cc]);
      int w3 = __builtin_nontemporal_load(&srt[e + 12 + cc]);
      unsigned v[16];
#pragma unroll
      for (int k = 0; k < 4; k++) {
        int s0 = __shfl(w0, gb + k, 64);
        int s1 = __shfl(w1, gb + k, 64);
        int s2 = __shfl(w2, gb + k, 64);
        int s3 = __shfl(w3, gb + k, 64);
        v[0 + k] = src32[(size_t)s0 * 4 + cc];
        v[4 + k] = src32[(size_t)s1 * 4 + cc];
        v[8 + k] = src32[(size_t)s2 * 4 + cc];
        v[12 + k] = src32[(size_t)s3 * 4 + cc];
      }
#pragma unroll
      for (int k = 0; k < 4; k++) {
        a0 += bf2x2(v[0 + k]);
        a1 += bf2x2(v[4 + k]);
        a2 += bf2x2(v[8 + k]);
        a3 += bf2x2(v[12 + k]);
      }
    }
    for (; e + 4 <= end; e += 4) {
      int w0 = __builtin_nontemporal_load(&srt[e + cc]);
      int s0 = __shfl(w0, gb + 0, 64);
      int s1 = __shfl(w0, gb + 1, 64);
      int s2 = __shfl(w0, gb + 2, 64);
      int s3 = __shfl(w0, gb + 3, 64);
      a0 += bf2x2(src32[(size_t)s0 * 4 + cc]);
      a1 += bf2x2(src32[(size_t)s1 * 4 + cc]);
      a2 += bf2x2(src32[(size_t)s2 * 4 + cc]);
      a3 += bf2x2(src32[(size_t)s3 * 4 + cc]);
    }
    for (; e < end; e++) {
      int s = __builtin_nontemporal_load(&srt[e]);
      a0 += bf2x2(src32[(size_t)s * 4 + cc]);
    }
    f32x2 acc = (a0 + a1) + (a2 + a3);
    dsl[(size_t)row * 4 + cc] = pack2bf(acc.x, acc.y);  // same-XCD full-line writes
  }
}

// ---------------- phase B: TWO fused tap GEMMs per dispatch, 64-row tiles ----------------
__global__ void __launch_bounds__(256) k_tap2(const u16* __restrict__ slA,
                                              const u16* __restrict__ slB,
                                              float* __restrict__ x,
                                              const float* __restrict__ tWb,
                                              const float* __restrict__ tbb,
                                              const float* __restrict__ tWg,
                                              const float* __restrict__ tbg,
                                              int idxA, int idxB,
                                              float* __restrict__ stats) {
  __shared__ float Ws[4096];
  __shared__ unsigned stage[64][36];  // pad 36 -> clean banks
  __shared__ float sst[128];
  const int tile = blockIdx.x;
  const bool isBus = tile < NTILE_BUS;
  const int row0 = tile * 64;
  const int tid = threadIdx.x;
  const int lane = tid & 63;
  const int sub = lane & 31;
  const int c0 = sub * 2;
  const int h32 = (lane >> 5) * 32;
  const int hw = tid >> 5;  // half-wave id (0..7): local rows hw*8..hw*8+7
  const float* Wbase = isBus ? tWb : tWg;
  const float* bbase = isBus ? tbb : tbg;
  f32x2 bsum;
  bsum.x = bbase[(size_t)idxA * 64 + c0] + bbase[(size_t)idxB * 64 + c0];
  bsum.y = bbase[(size_t)idxA * 64 + c0 + 1] + bbase[(size_t)idxB * 64 + c0 + 1];
  f32x2 z[8];
#pragma unroll
  for (int i = 0; i < 8; i++) z[i] = bsum;
  const u16* sls[2] = {slA, slB};
  const int idxs[2] = {idxA, idxB};
  for (int s = 0; s < 2; s++) {
    __syncthreads();  // protect Ws/stage from previous round's readers
    const float* W = Wbase + (size_t)idxs[s] * 4096;
    for (int i = tid; i < 4096; i += 256) Ws[i] = W[i];
    const unsigned* sl = (const unsigned*)sls[s];
    int r = tid >> 2, cc = tid & 3;
#pragma unroll
    for (int g = 0; g < 8; g++)  // 1 KB contiguous per slab stripe
      stage[r][g * 4 + cc] =
          __builtin_nontemporal_load(&sl[((size_t)g * NALL + row0 + r) * 4 + cc]);
    __syncthreads();
#pragma unroll
    for (int i = 0; i < 8; i++) {
      int lr = hw * 8 + i;
      f32x2 acc = bf2x2(stage[lr][sub]);
      f32x2 zz = z[i];
#pragma unroll
      for (int t = 0; t < 32; t++) {
        float ax = __shfl(acc.x, h32 + t, 64);
        float ay = __shfl(acc.y, h32 + t, 64);
        f32x2 w0 = *(const f32x2*)&Ws[(2 * t) * 64 + c0];
        f32x2 w1 = *(const f32x2*)&Ws[(2 * t + 1) * 64 + c0];
        zz.x = fmaf(ax, w0.x, zz.x);
        zz.y = fmaf(ax, w0.y, zz.y);
        zz.x = fmaf(ay, w1.x, zz.x);
        zz.y = fmaf(ay, w1.y, zz.y);
      }
      z[i] = zz;
    }
  }
  f32x2 ls = {0.f, 0.f}, ls2 = {0.f, 0.f};
#pragma unroll
  for (int i = 0; i < 8; i++) {
    int row = row0 + hw * 8 + i;
    size_t idx = (size_t)row * 64 + c0;
    f32x2 xv = __builtin_nontemporal_load((const f32x2*)&x[idx]);
    f32x2 xo = xv + z[i];
    __builtin_nontemporal_store(xo, (f32x2*)&x[idx]);
    ls += xo;
    ls2 += xo * xo;
  }
  if (stats) {
    if (tid < 128) sst[tid] = 0.f;
    __syncthreads();
    atomicAdd(&sst[c0], ls.x);
    atomicAdd(&sst[c0 + 1], ls.y);
    atomicAdd(&sst[64 + c0], ls2.x);
    atomicAdd(&sst[64 + c0 + 1], ls2.y);
    __syncthreads();
    if (tid < 128) atomicAdd(&stats[(isBus ? 0 : 128) + tid], sst[tid]);
  }
}

// ---------------- merged readout ----------------
__global__ void __launch_bounds__(256) k_readout(const float* __restrict__ x,
                                                 const float* __restrict__ Wb,
                                                 const float* __restrict__ bb_,
                                                 const float* __restrict__ Wg,
                                                 const float* __restrict__ bg_,
                                                 float* __restrict__ out) {
  __shared__ float WsB[2048];
  __shared__ float WsG[2048];
  __shared__ float bsB[32];
  __shared__ float bsG[32];
  for (int i = threadIdx.x; i < 2048; i += 256) {
    WsB[i] = Wb[i];
    WsG[i] = Wg[i];
  }
  if (threadIdx.x < 32) {
    bsB[threadIdx.x] = bb_[threadIdx.x];
    bsG[threadIdx.x] = bg_[threadIdx.x];
  }
  __syncthreads();
  int lane = threadIdx.x & 63;
  int ch = lane & 31;
  int w = (blockIdx.x * blockDim.x + threadIdx.x) >> 6;
  int nw = (gridDim.x * blockDim.x) >> 6;
  for (int g = w; g < NALL; g += nw) {
    bool isBus = g < NBUS;
    const float* Ws = isBus ? WsB : WsG;
    float v = __builtin_nontemporal_load(&x[(size_t)g * 64 + lane]);
    float acc = isBus ? bsB[ch] : bsG[ch];
#pragma unroll
    for (int i = 0; i < 64; i++) {
      float xi = __shfl(v, i, 64);
      acc = fmaf(xi, Ws[i * 32 + ch], acc);
    }
    if (lane < 32) out[(size_t)g * 32 + ch] = acc;
  }
}

extern "C" void kernel_launch(void* const* d_in, const int* in_sizes, int n_in,
                              void* d_out, int out_size, void* d_ws, size_t ws_size,
                              hipStream_t stream) {
  const float* x_bus = (const float*)d_in[0];
  const float* x_gen = (const float*)d_in[1];
  const float* riWb = (const float*)d_in[2];
  const float* ribb = (const float*)d_in[3];
  const float* riWg = (const float*)d_in[4];
  const float* ribg = (const float*)d_in[5];
  const float* bng_b = (const float*)d_in[6];
  const float* bnb_b = (const float*)d_in[7];
  const float* bng_g = (const float*)d_in[8];
  const float* bnb_g = (const float*)d_in[9];
  const float* tWb = (const float*)d_in[10];
  const float* tbb = (const float*)d_in[11];
  const float* tWg = (const float*)d_in[12];
  const float* tbg = (const float*)d_in[13];
  const float* roWb = (const float*)d_in[14];
  const float* robb = (const float*)d_in[15];
  const float* roWg = (const float*)d_in[16];
  const float* robg = (const float*)d_in[17];
  const int* ebb = (const int*)d_in[18];
  const int* gb_src = (const int*)d_in[19];
  const int* gb_dst = (const int*)d_in[20];
  const int* bg_src = (const int*)d_in[21];
  const int* bg_dst = (const int*)d_in[22];
  const int* bb_src = ebb;
  const int* bb_dst = ebb + NEBB;

  // ---- workspace layout (256B aligned segments) ----
  char* p = (char*)d_ws;
  auto take = [&](size_t bytes) -> void* {
    void* r = (void*)p;
    p += (bytes + 255) & ~(size_t)255;
    return r;
  };
  float* x = (float*)take((size_t)NALL * 64 * 4);  // bus rows [0,NBUS), gen rows after
  u16* b0 = (u16*)take((size_t)NALL * 64 * 2);     // sliced bf16 shift-state buffers
  u16* b1 = (u16*)take((size_t)NALL * 64 * 2);
  u16* b2 = (u16*)take((size_t)NALL * 64 * 2);
  int* bus_off = (int*)take((size_t)(NBUS + 1) * 4);
  int* bus_srt = (int*)take((size_t)NEBUS * 4);
  int* bg_off = (int*)take((size_t)(NGEN + 1) * 4);
  int* bg_srt = (int*)take((size_t)NEBG * 4);
  int* bsums = (int*)take(256 * 4);
  // zero-initialized group (contiguous -> single memset)
  int* bus_cur = (int*)take((size_t)NBUS * 4);
  int* bg_cur = (int*)take((size_t)NGEN * 4);
  float* stats0 = (float*)take(256 * 4);  // [bus s, bus s2, gen s, gen s2]
  float* stats1 = (float*)take(256 * 4);
  size_t zlen = (char*)p - (char*)bus_cur;
  if ((size_t)(p - (char*)d_ws) > ws_size) return;  // ws too small -> visible validation failure

  // ---- CSR build (merged bus CSR: bb edges + gb edges with src+NBUS) ----
  hipMemsetAsync(bus_cur, 0, zlen, stream);

  k_hist_sl<<<2048, 256, 0, stream>>>(bb_dst, gb_dst, bg_dst, bus_cur, bg_cur);

  k_scan1<<<128, 256, 0, stream>>>(bus_cur, bus_off, bsums, NBUS);
  k_scan2<<<1, 256, 0, stream>>>(bsums, 128);
  k_scan3<<<512, 256, 0, stream>>>(bus_off, bus_cur, bsums, NBUS, NEBUS);

  k_scan1<<<32, 256, 0, stream>>>(bg_cur, bg_off, bsums, NGEN);
  k_scan2<<<1, 256, 0, stream>>>(bsums, 32);
  k_scan3<<<128, 256, 0, stream>>>(bg_off, bg_cur, bsums, NGEN, NEBG);

  k_fill_sl<<<2560, 256, 0, stream>>>(bb_src, bb_dst, gb_src, gb_dst, bg_src, bg_dst,
                                      bus_cur, bg_cur, bus_srt, bg_srt);

  // ---- readin (+ layer-0 BN stats) ----
  k_readin<<<5120, 256, 0, stream>>>(x_bus, x_gen, riWb, ribb, riWg, ribg, x, stats0);

  // ---- residual blocks: tap0 -> A,A,B2 -> A,A,B2 ----
  for (int l = 0; l < 2; l++) {
    float* statsL = (l == 0) ? stats0 : stats1;
    k_norm_tap0<<<NTILE, 256, 0, stream>>>(x, b0, statsL,
                                           bng_b + l * 64, bnb_b + l * 64,
                                           bng_g + l * 64, bnb_g + l * 64,
                                           tWb, tbb, tWg, tbg, l * 5);
    k_gather<<<2048, 256, 0, stream>>>(bus_off, bus_srt, bg_off, bg_srt, b0, b1);
    k_gather<<<2048, 256, 0, stream>>>(bus_off, bus_srt, bg_off, bg_srt, b1, b2);
    k_tap2<<<NTILE, 256, 0, stream>>>(b1, b2, x, tWb, tbb, tWg, tbg,
                                      l * 5 + 1, l * 5 + 2, (float*)nullptr);
    k_gather<<<2048, 256, 0, stream>>>(bus_off, bus_srt, bg_off, bg_srt, b2, b0);
    k_gather<<<2048, 256, 0, stream>>>(bus_off, bus_srt, bg_off, bg_srt, b0, b1);
    k_tap2<<<NTILE, 256, 0, stream>>>(b0, b1, x, tWb, tbb, tWg, tbg,
                                      l * 5 + 3, l * 5 + 4,
                                      (l == 0) ? stats1 : (float*)nullptr);
  }

  // ---- readout ----
  k_readout<<<5120, 256, 0, stream>>>(x, roWb, robb, roWg, robg, (float*)d_out);
}

// Round 9
// 1601.590 us; speedup vs baseline: 1.8163x; 1.8163x over previous
//
#include <hip/hip_runtime.h>

#define NBUS 131072
#define NGEN 32768
#define NALL (NBUS + NGEN)
#define NEBB 2097152
#define NEGB 65536
#define NEBG 65536
#define NEBUS (NEBB + NEGB)   // merged bus-dest CSR (bb + gb)
#define NTILE (NALL / 64)     // 2560
#define NTILE_BUS (NBUS / 64) // 2048

typedef float f32x2 __attribute__((ext_vector_type(2)));
typedef unsigned short u16;

__device__ inline f32x2 bf2x2(unsigned v) {  // unpack 2 bf16 (packed u32) -> 2 f32
  f32x2 r;
  r.x = __builtin_bit_cast(float, v << 16);
  r.y = __builtin_bit_cast(float, v & 0xFFFF0000u);
  return r;
}
__device__ inline u16 f2bf(float f) {  // round-to-nearest-even
  unsigned u = __builtin_bit_cast(unsigned, f);
  unsigned r = u + 0x7FFFu + ((u >> 16) & 1u);
  return (u16)(r >> 16);
}
__device__ inline unsigned pack2bf(float a, float b) {
  return (unsigned)f2bf(a) | ((unsigned)f2bf(b) << 16);
}

// ---------------- CSR build: XCD-sliced hist (cached reads, 4-way MLP) ----------------
__global__ void __launch_bounds__(256) k_hist_sl(const int* __restrict__ bbDst,
                                                 const int* __restrict__ gbDst,
                                                 const int* __restrict__ bgDst,
                                                 int* __restrict__ busCnt,
                                                 int* __restrict__ bgCnt) {
  const int g = blockIdx.x & 7;
  const int blk = blockIdx.x >> 3;
  const int nblk = gridDim.x >> 3;
  const int start = blk * 256 + threadIdx.x;
  const int S = nblk * 256;
  int i = start;
  for (; i + 3 * S < NEBB; i += 4 * S) {
    int d0 = bbDst[i], d1 = bbDst[i + S], d2 = bbDst[i + 2 * S], d3 = bbDst[i + 3 * S];
    if ((d0 >> 14) == g) atomicAdd(&busCnt[d0], 1);
    if ((d1 >> 14) == g) atomicAdd(&busCnt[d1], 1);
    if ((d2 >> 14) == g) atomicAdd(&busCnt[d2], 1);
    if ((d3 >> 14) == g) atomicAdd(&busCnt[d3], 1);
  }
  for (; i < NEBB; i += S) {
    int d = bbDst[i];
    if ((d >> 14) == g) atomicAdd(&busCnt[d], 1);
  }
  for (i = start; i < NEGB; i += S) {
    int d = gbDst[i];
    if ((d >> 14) == g) atomicAdd(&busCnt[d], 1);
  }
  for (i = start; i < NEBG; i += S) {
    int d = bgDst[i];
    if ((d >> 12) == g) atomicAdd(&bgCnt[d], 1);
  }
}

__global__ void k_scan1(const int* __restrict__ in, int* __restrict__ out,
                        int* __restrict__ bsums, int n) {
  __shared__ int sh[256];
  int t = threadIdx.x;
  int base = blockIdx.x * 1024 + t * 4;
  int v0 = (base + 0 < n) ? in[base + 0] : 0;
  int v1 = (base + 1 < n) ? in[base + 1] : 0;
  int v2 = (base + 2 < n) ? in[base + 2] : 0;
  int v3 = (base + 3 < n) ? in[base + 3] : 0;
  int t0 = v0, t1 = t0 + v1, t2 = t1 + v2, t3 = t2 + v3;
  sh[t] = t3;
  __syncthreads();
  for (int off = 1; off < 256; off <<= 1) {
    int x = (t >= off) ? sh[t - off] : 0;
    __syncthreads();
    sh[t] += x;
    __syncthreads();
  }
  int excl = (t > 0) ? sh[t - 1] : 0;
  if (base + 0 < n) out[base + 0] = excl;
  if (base + 1 < n) out[base + 1] = excl + t0;
  if (base + 2 < n) out[base + 2] = excl + t1;
  if (base + 3 < n) out[base + 3] = excl + t2;
  if (t == 255) bsums[blockIdx.x] = sh[255];
}

__global__ void k_scan2(int* __restrict__ bsums, int nb) {
  __shared__ int sh[256];
  int t = threadIdx.x;
  int v = (t < nb) ? bsums[t] : 0;
  sh[t] = v;
  __syncthreads();
  for (int off = 1; off < 256; off <<= 1) {
    int x = (t >= off) ? sh[t - off] : 0;
    __syncthreads();
    sh[t] += x;
    __syncthreads();
  }
  int excl = (t > 0) ? sh[t - 1] : 0;
  if (t < nb) bsums[t] = excl;
}

__global__ void k_scan3(int* __restrict__ off, int* __restrict__ cur,
                        const int* __restrict__ bsums, int n, int E) {
  int stride = gridDim.x * blockDim.x;
  for (int i = blockIdx.x * blockDim.x + threadIdx.x; i < n; i += stride) {
    int o = off[i] + bsums[i >> 10];
    off[i] = o;
    cur[i] = o;
  }
  if (blockIdx.x == 0 && threadIdx.x == 0) off[n] = E;
}

// ---------------- CSR fill: XCD-sliced (cached reads, 4-way MLP) ----------------
__global__ void __launch_bounds__(256) k_fill_sl(const int* __restrict__ bbSrc,
                                                 const int* __restrict__ bbDst,
                                                 const int* __restrict__ gbSrc,
                                                 const int* __restrict__ gbDst,
                                                 const int* __restrict__ bgSrc,
                                                 const int* __restrict__ bgDst,
                                                 int* __restrict__ busCur,
                                                 int* __restrict__ bgCur,
                                                 int* __restrict__ busSrt,
                                                 int* __restrict__ bgSrt) {
  const int g = blockIdx.x & 7;
  const int tid = threadIdx.x;
  if (blockIdx.x < 2048) {  // bus-bus edges
    const int blk = blockIdx.x >> 3;
    const int S = 256 * 256;
    int i = blk * 256 + tid;
    for (; i + 3 * S < NEBB; i += 4 * S) {
      int d0 = bbDst[i], d1 = bbDst[i + S], d2 = bbDst[i + 2 * S], d3 = bbDst[i + 3 * S];
      if ((d0 >> 14) == g) { int p = atomicAdd(&busCur[d0], 1); busSrt[p] = bbSrc[i]; }
      if ((d1 >> 14) == g) { int p = atomicAdd(&busCur[d1], 1); busSrt[p] = bbSrc[i + S]; }
      if ((d2 >> 14) == g) { int p = atomicAdd(&busCur[d2], 1); busSrt[p] = bbSrc[i + 2 * S]; }
      if ((d3 >> 14) == g) { int p = atomicAdd(&busCur[d3], 1); busSrt[p] = bbSrc[i + 3 * S]; }
    }
    for (; i < NEBB; i += S) {
      int d = bbDst[i];
      if ((d >> 14) == g) { int p = atomicAdd(&busCur[d], 1); busSrt[p] = bbSrc[i]; }
    }
  } else if (blockIdx.x < 2304) {  // gen->bus edges (src offset +NBUS)
    const int blk = (blockIdx.x - 2048) >> 3;
    const int S = 32 * 256;
    for (int i = blk * 256 + tid; i < NEGB; i += S) {
      int d = gbDst[i];
      if ((d >> 14) == g) { int p = atomicAdd(&busCur[d], 1); busSrt[p] = gbSrc[i] + NBUS; }
    }
  } else {  // bus->gen edges
    const int blk = (blockIdx.x - 2304) >> 3;
    const int S = 32 * 256;
    for (int i = blk * 256 + tid; i < NEBG; i += S) {
      int d = bgDst[i];
      if ((d >> 12) == g) { int p = atomicAdd(&bgCur[d], 1); bgSrt[p] = bgSrc[i]; }
    }
  }
}

// ---------------- merged readin (bus+gen rows) + fused BN-stats ----------------
__global__ void __launch_bounds__(256) k_readin(const float* __restrict__ xbus,
                                                const float* __restrict__ xgen,
                                                const float* __restrict__ Wb,
                                                const float* __restrict__ bb_,
                                                const float* __restrict__ Wg,
                                                const float* __restrict__ bg_,
                                                float* __restrict__ y,
                                                float* __restrict__ stats) {
  __shared__ float WsB[2048];
  __shared__ float WsG[2048];
  __shared__ float shs[4][64];
  __shared__ float shs2[4][64];
  for (int i = threadIdx.x; i < 2048; i += 256) {
    WsB[i] = Wb[i];
    WsG[i] = Wg[i];
  }
  __syncthreads();
  int lane = threadIdx.x & 63;
  int wib = threadIdx.x >> 6;
  float bvB = bb_[lane], bvG = bg_[lane];
  int w = (blockIdx.x * blockDim.x + threadIdx.x) >> 6;
  int nw = (gridDim.x * blockDim.x) >> 6;
  float lsB = 0.f, ls2B = 0.f, lsG = 0.f, ls2G = 0.f;
  for (int g = w; g < NALL; g += nw) {
    bool isBus = g < NBUS;
    const float* xin = isBus ? xbus : xgen;
    int rl = isBus ? g : g - NBUS;
    const float* Ws = isBus ? WsB : WsG;
    float v = xin[(size_t)rl * 32 + (lane & 31)];
    float acc = isBus ? bvB : bvG;
#pragma unroll
    for (int i = 0; i < 32; i++) {
      float xi = __shfl(v, i, 64);
      acc = fmaf(xi, Ws[i * 64 + lane], acc);
    }
    y[(size_t)g * 64 + lane] = acc;
    if (isBus) {
      lsB += acc;
      ls2B = fmaf(acc, acc, ls2B);
    } else {
      lsG += acc;
      ls2G = fmaf(acc, acc, ls2G);
    }
  }
  shs[wib][lane] = lsB;
  shs2[wib][lane] = ls2B;
  __syncthreads();
  if (threadIdx.x < 64) {
    int c = threadIdx.x;
    atomicAdd(&stats[c], shs[0][c] + shs[1][c] + shs[2][c] + shs[3][c]);
  } else if (threadIdx.x < 128) {
    int c = threadIdx.x & 63;
    atomicAdd(&stats[64 + c], shs2[0][c] + shs2[1][c] + shs2[2][c] + shs2[3][c]);
  }
  __syncthreads();
  shs[wib][lane] = lsG;
  shs2[wib][lane] = ls2G;
  __syncthreads();
  if (threadIdx.x < 64) {
    int c = threadIdx.x;
    atomicAdd(&stats[128 + c], shs[0][c] + shs[1][c] + shs[2][c] + shs[3][c]);
  } else if (threadIdx.x < 128) {
    int c = threadIdx.x & 63;
    atomicAdd(&stats[192 + c], shs2[0][c] + shs2[1][c] + shs2[2][c] + shs2[3][c]);
  }
}

// ---------------- BN-finalize + normalize + lrelu + tap0, 64-row tiles (row-major out) ----
__global__ void __launch_bounds__(256) k_norm_tap0(float* __restrict__ x,
                                                   u16* __restrict__ c0,
                                                   const float* __restrict__ stats,
                                                   const float* __restrict__ gammaB,
                                                   const float* __restrict__ betaB,
                                                   const float* __restrict__ gammaG,
                                                   const float* __restrict__ betaG,
                                                   const float* __restrict__ tWb,
                                                   const float* __restrict__ tbb,
                                                   const float* __restrict__ tWg,
                                                   const float* __restrict__ tbg,
                                                   int tapIdx) {
  __shared__ float Ws[4096];
  int tile = blockIdx.x;
  bool isBus = tile < NTILE_BUS;
  const float* W = (isBus ? tWb : tWg) + (size_t)tapIdx * 4096;
  for (int i = threadIdx.x; i < 4096; i += 256) Ws[i] = W[i];
  int lane = threadIdx.x & 63;
  int wv = threadIdx.x >> 6;
  int so = isBus ? 0 : 128;
  float invN = isBus ? (1.0f / NBUS) : (1.0f / NGEN);
  float m = stats[so + lane] * invN;
  float m2 = stats[so + 64 + lane] * invN;
  float rs = rsqrtf(m2 - m * m + 1e-5f);
  float scale = (isBus ? gammaB : gammaG)[lane] * rs;
  float shift = (isBus ? betaB : betaG)[lane] - m * scale;
  float bv = ((isBus ? tbb : tbg) + (size_t)tapIdx * 64)[lane];
  __syncthreads();
  unsigned* cu = (unsigned*)c0;
  int row0 = tile * 64 + wv * 16;
  for (int i = 0; i < 16; i++) {
    int row = row0 + i;
    size_t idx = (size_t)row * 64 + lane;
    float xv = x[idx];
    float y = fmaf(xv, scale, shift);
    y = (y >= 0.f) ? y : 0.01f * y;
    float ypair = __shfl(y, lane ^ 1, 64);
    if ((lane & 1) == 0)  // even lane packs (even,odd) channels, row-major
      cu[(size_t)row * 32 + (lane >> 1)] = pack2bf(y, ypair);
    float acc = bv;
#pragma unroll
    for (int t = 0; t < 64; t++) {
      float yi = __shfl(y, t, 64);
      acc = fmaf(yi, Ws[t * 64 + lane], acc);
    }
    x[idx] = xv + acc;
  }
}

// ---------------- phase A: CSR gather, row-major bf16, 8 lanes/row, uint4 loads ----------
// One edge = one 128 B row pulled by an 8-lane group (16 B/lane). 8-deep masked unroll
// -> 8 srt + 8 uint4 gathers in flight per lane; working set is L3-resident.
__global__ void __launch_bounds__(256) k_gather(const int* __restrict__ busOff,
                                                const int* __restrict__ busSrt,
                                                const int* __restrict__ bgOff,
                                                const int* __restrict__ bgSrt,
                                                const u16* __restrict__ src,
                                                u16* __restrict__ dst) {
  const int lane = threadIdx.x & 63;
  const int wv = threadIdx.x >> 6;
  const int grp = lane >> 3;  // row slot within wave (0..7)
  const int sub = lane & 7;   // 16 B chunk within the 128 B row
  const unsigned* s32 = (const unsigned*)src;
  unsigned* d32 = (unsigned*)dst;
  int rowBase = (blockIdx.x * 4 + wv) * 8;
  const int rstride = gridDim.x * 32;
  for (int row0 = rowBase; row0 < NALL; row0 += rstride) {
    int row = row0 + grp;
    int beg, end;
    const int* srt;
    if (row < NBUS) {
      beg = busOff[row];
      end = busOff[row + 1];
      srt = busSrt;
    } else {
      beg = bgOff[row - NBUS];
      end = bgOff[row - NBUS + 1];
      srt = bgSrt;
    }
    f32x2 a0 = {0.f, 0.f}, a1 = {0.f, 0.f}, a2 = {0.f, 0.f}, a3 = {0.f, 0.f};
    for (int e = beg; e < end; e += 8) {
      uint4 v[8];
      int last = end - 1;
#pragma unroll
      for (int j = 0; j < 8; j++) {
        int idx = e + j;
        bool ok = idx < end;
        if (!ok) idx = last;
        int s = srt[idx];
        uint4 vv = *(const uint4*)&s32[(size_t)s * 32 + sub * 4];
        if (!ok) { vv.x = 0; vv.y = 0; vv.z = 0; vv.w = 0; }
        v[j] = vv;
      }
#pragma unroll
      for (int j = 0; j < 8; j++) {
        a0 += bf2x2(v[j].x);
        a1 += bf2x2(v[j].y);
        a2 += bf2x2(v[j].z);
        a3 += bf2x2(v[j].w);
      }
    }
    uint4 o;
    o.x = pack2bf(a0.x, a0.y);
    o.y = pack2bf(a1.x, a1.y);
    o.z = pack2bf(a2.x, a2.y);
    o.w = pack2bf(a3.x, a3.y);
    *(uint4*)&d32[(size_t)row * 32 + sub * 4] = o;  // wave writes 8 contiguous rows
  }
}

// ---------------- phase B: TWO fused tap GEMMs per dispatch, direct row-major reads ------
__global__ void __launch_bounds__(256) k_tap2(const u16* __restrict__ cA,
                                              const u16* __restrict__ cB,
                                              float* __restrict__ x,
                                              const float* __restrict__ tWb,
                                              const float* __restrict__ tbb,
                                              const float* __restrict__ tWg,
                                              const float* __restrict__ tbg,
                                              int idxA, int idxB,
                                              float* __restrict__ stats) {
  __shared__ float Ws[4096];
  __shared__ float sst[128];
  const int tile = blockIdx.x;
  const bool isBus = tile < NTILE_BUS;
  const int row0 = tile * 64;
  const int tid = threadIdx.x;
  const int lane = tid & 63;
  const int sub = lane & 31;
  const int c0 = sub * 2;
  const int h32 = (lane >> 5) * 32;
  const int hw = tid >> 5;  // half-wave id (0..7): local rows hw*8..hw*8+7
  const float* Wbase = isBus ? tWb : tWg;
  const float* bbase = isBus ? tbb : tbg;
  f32x2 bsum;
  bsum.x = bbase[(size_t)idxA * 64 + c0] + bbase[(size_t)idxB * 64 + c0];
  bsum.y = bbase[(size_t)idxA * 64 + c0 + 1] + bbase[(size_t)idxB * 64 + c0 + 1];
  f32x2 z[8];
#pragma unroll
  for (int i = 0; i < 8; i++) z[i] = bsum;
  const u16* cs[2] = {cA, cB};
  const int idxs[2] = {idxA, idxB};
  for (int s = 0; s < 2; s++) {
    __syncthreads();  // protect Ws from previous round's readers
    const float* W = Wbase + (size_t)idxs[s] * 4096;
    for (int i = tid; i < 4096; i += 256) Ws[i] = W[i];
    const unsigned* c32 = (const unsigned*)cs[s];
    __syncthreads();
#pragma unroll
    for (int i = 0; i < 8; i++) {
      int row = row0 + hw * 8 + i;
      f32x2 acc = bf2x2(c32[(size_t)row * 32 + sub]);  // coalesced 128 B/row
      f32x2 zz = z[i];
#pragma unroll
      for (int t = 0; t < 32; t++) {
        float ax = __shfl(acc.x, h32 + t, 64);
        float ay = __shfl(acc.y, h32 + t, 64);
        f32x2 w0 = *(const f32x2*)&Ws[(2 * t) * 64 + c0];
        f32x2 w1 = *(const f32x2*)&Ws[(2 * t + 1) * 64 + c0];
        zz.x = fmaf(ax, w0.x, zz.x);
        zz.y = fmaf(ax, w0.y, zz.y);
        zz.x = fmaf(ay, w1.x, zz.x);
        zz.y = fmaf(ay, w1.y, zz.y);
      }
      z[i] = zz;
    }
  }
  f32x2 ls = {0.f, 0.f}, ls2 = {0.f, 0.f};
#pragma unroll
  for (int i = 0; i < 8; i++) {
    int row = row0 + hw * 8 + i;
    size_t idx = (size_t)row * 64 + c0;
    f32x2 xv = *(const f32x2*)&x[idx];
    f32x2 xo = xv + z[i];
    *(f32x2*)&x[idx] = xo;
    ls += xo;
    ls2 += xo * xo;
  }
  if (stats) {
    if (tid < 128) sst[tid] = 0.f;
    __syncthreads();
    atomicAdd(&sst[c0], ls.x);
    atomicAdd(&sst[c0 + 1], ls.y);
    atomicAdd(&sst[64 + c0], ls2.x);
    atomicAdd(&sst[64 + c0 + 1], ls2.y);
    __syncthreads();
    if (tid < 128) atomicAdd(&stats[(isBus ? 0 : 128) + tid], sst[tid]);
  }
}

// ---------------- merged readout ----------------
__global__ void __launch_bounds__(256) k_readout(const float* __restrict__ x,
                                                 const float* __restrict__ Wb,
                                                 const float* __restrict__ bb_,
                                                 const float* __restrict__ Wg,
                                                 const float* __restrict__ bg_,
                                                 float* __restrict__ out) {
  __shared__ float WsB[2048];
  __shared__ float WsG[2048];
  __shared__ float bsB[32];
  __shared__ float bsG[32];
  for (int i = threadIdx.x; i < 2048; i += 256) {
    WsB[i] = Wb[i];
    WsG[i] = Wg[i];
  }
  if (threadIdx.x < 32) {
    bsB[threadIdx.x] = bb_[threadIdx.x];
    bsG[threadIdx.x] = bg_[threadIdx.x];
  }
  __syncthreads();
  int lane = threadIdx.x & 63;
  int ch = lane & 31;
  int w = (blockIdx.x * blockDim.x + threadIdx.x) >> 6;
  int nw = (gridDim.x * blockDim.x) >> 6;
  for (int g = w; g < NALL; g += nw) {
    bool isBus = g < NBUS;
    const float* Ws = isBus ? WsB : WsG;
    float v = __builtin_nontemporal_load(&x[(size_t)g * 64 + lane]);
    float acc = isBus ? bsB[ch] : bsG[ch];
#pragma unroll
    for (int i = 0; i < 64; i++) {
      float xi = __shfl(v, i, 64);
      acc = fmaf(xi, Ws[i * 32 + ch], acc);
    }
    if (lane < 32) out[(size_t)g * 32 + ch] = acc;
  }
}

extern "C" void kernel_launch(void* const* d_in, const int* in_sizes, int n_in,
                              void* d_out, int out_size, void* d_ws, size_t ws_size,
                              hipStream_t stream) {
  const float* x_bus = (const float*)d_in[0];
  const float* x_gen = (const float*)d_in[1];
  const float* riWb = (const float*)d_in[2];
  const float* ribb = (const float*)d_in[3];
  const float* riWg = (const float*)d_in[4];
  const float* ribg = (const float*)d_in[5];
  const float* bng_b = (const float*)d_in[6];
  const float* bnb_b = (const float*)d_in[7];
  const float* bng_g = (const float*)d_in[8];
  const float* bnb_g = (const float*)d_in[9];
  const float* tWb = (const float*)d_in[10];
  const float* tbb = (const float*)d_in[11];
  const float* tWg = (const float*)d_in[12];
  const float* tbg = (const float*)d_in[13];
  const float* roWb = (const float*)d_in[14];
  const float* robb = (const float*)d_in[15];
  const float* roWg = (const float*)d_in[16];
  const float* robg = (const float*)d_in[17];
  const int* ebb = (const int*)d_in[18];
  const int* gb_src = (const int*)d_in[19];
  const int* gb_dst = (const int*)d_in[20];
  const int* bg_src = (const int*)d_in[21];
  const int* bg_dst = (const int*)d_in[22];
  const int* bb_src = ebb;
  const int* bb_dst = ebb + NEBB;

  // ---- workspace layout (256B aligned segments) ----
  char* p = (char*)d_ws;
  auto take = [&](size_t bytes) -> void* {
    void* r = (void*)p;
    p += (bytes + 255) & ~(size_t)255;
    return r;
  };
  float* x = (float*)take((size_t)NALL * 64 * 4);  // bus rows [0,NBUS), gen rows after
  u16* b0 = (u16*)take((size_t)NALL * 64 * 2);     // row-major bf16 shift-state buffers
  u16* b1 = (u16*)take((size_t)NALL * 64 * 2);
  u16* b2 = (u16*)take((size_t)NALL * 64 * 2);
  int* bus_off = (int*)take((size_t)(NBUS + 1) * 4);
  int* bus_srt = (int*)take((size_t)NEBUS * 4);
  int* bg_off = (int*)take((size_t)(NGEN + 1) * 4);
  int* bg_srt = (int*)take((size_t)NEBG * 4);
  int* bsums = (int*)take(256 * 4);
  // zero-initialized group (contiguous -> single memset)
  int* bus_cur = (int*)take((size_t)NBUS * 4);
  int* bg_cur = (int*)take((size_t)NGEN * 4);
  float* stats0 = (float*)take(256 * 4);  // [bus s, bus s2, gen s, gen s2]
  float* stats1 = (float*)take(256 * 4);
  size_t zlen = (char*)p - (char*)bus_cur;
  if ((size_t)(p - (char*)d_ws) > ws_size) return;  // ws too small -> visible validation failure

  // ---- CSR build (merged bus CSR: bb edges + gb edges with src+NBUS) ----
  hipMemsetAsync(bus_cur, 0, zlen, stream);

  k_hist_sl<<<2048, 256, 0, stream>>>(bb_dst, gb_dst, bg_dst, bus_cur, bg_cur);

  k_scan1<<<128, 256, 0, stream>>>(bus_cur, bus_off, bsums, NBUS);
  k_scan2<<<1, 256, 0, stream>>>(bsums, 128);
  k_scan3<<<512, 256, 0, stream>>>(bus_off, bus_cur, bsums, NBUS, NEBUS);

  k_scan1<<<32, 256, 0, stream>>>(bg_cur, bg_off, bsums, NGEN);
  k_scan2<<<1, 256, 0, stream>>>(bsums, 32);
  k_scan3<<<128, 256, 0, stream>>>(bg_off, bg_cur, bsums, NGEN, NEBG);

  k_fill_sl<<<2560, 256, 0, stream>>>(bb_src, bb_dst, gb_src, gb_dst, bg_src, bg_dst,
                                      bus_cur, bg_cur, bus_srt, bg_srt);

  // ---- readin (+ layer-0 BN stats) ----
  k_readin<<<5120, 256, 0, stream>>>(x_bus, x_gen, riWb, ribb, riWg, ribg, x, stats0);

  // ---- residual blocks: tap0 -> A,A,B2 -> A,A,B2 ----
  for (int l = 0; l < 2; l++) {
    float* statsL = (l == 0) ? stats0 : stats1;
    k_norm_tap0<<<NTILE, 256, 0, stream>>>(x, b0, statsL,
                                           bng_b + l * 64, bnb_b + l * 64,
                                           bng_g + l * 64, bnb_g + l * 64,
                                           tWb, tbb, tWg, tbg, l * 5);
    k_gather<<<2560, 256, 0, stream>>>(bus_off, bus_srt, bg_off, bg_srt, b0, b1);
    k_gather<<<2560, 256, 0, stream>>>(bus_off, bus_srt, bg_off, bg_srt, b1, b2);
    k_tap2<<<NTILE, 256, 0, stream>>>(b1, b2, x, tWb, tbb, tWg, tbg,
                                      l * 5 + 1, l * 5 + 2, (float*)nullptr);
    k_gather<<<2560, 256, 0, stream>>>(bus_off, bus_srt, bg_off, bg_srt, b2, b0);
    k_gather<<<2560, 256, 0, stream>>>(bus_off, bus_srt, bg_off, bg_srt, b0, b1);
    k_tap2<<<NTILE, 256, 0, stream>>>(b0, b1, x, tWb, tbb, tWg, tbg,
                                      l * 5 + 3, l * 5 + 4,
                                      (l == 0) ? stats1 : (float*)nullptr);
  }

  // ---- readout ----
  k_readout<<<5120, 256, 0, stream>>>(x, roWb, robb, roWg, robg, (float*)d_out);
}

// Round 10
// 918.048 us; speedup vs baseline: 3.1687x; 1.7446x over previous
//
#include <hip/hip_runtime.h>

#define NBUS 131072
#define NGEN 32768
#define NALL (NBUS + NGEN)
#define NEBB 2097152
#define NEGB 65536
#define NEBG 65536
#define NEBUS (NEBB + NEGB)   // merged bus-dest CSR (bb + gb)
#define NTILE (NALL / 64)     // 2560
#define NTILE_BUS (NBUS / 64) // 2048

typedef float f32x2 __attribute__((ext_vector_type(2)));
typedef float f32x4 __attribute__((ext_vector_type(4)));
typedef short s16x8 __attribute__((ext_vector_type(8)));
typedef unsigned short u16;

__device__ inline f32x2 bf2x2(unsigned v) {  // unpack 2 bf16 (packed u32) -> 2 f32
  f32x2 r;
  r.x = __builtin_bit_cast(float, v << 16);
  r.y = __builtin_bit_cast(float, v & 0xFFFF0000u);
  return r;
}
__device__ inline u16 f2bf(float f) {  // round-to-nearest-even
  unsigned u = __builtin_bit_cast(unsigned, f);
  unsigned r = u + 0x7FFFu + ((u >> 16) & 1u);
  return (u16)(r >> 16);
}
__device__ inline unsigned pack2bf(float a, float b) {
  return (unsigned)f2bf(a) | ((unsigned)f2bf(b) << 16);
}

// ---------------- weight prep: bf16 transposed [n][k] layouts ----------------
// wt: 20 matrices (bus taps 0..9, gen taps 10..19), each [64 n][64 k] bf16.
// rot: 2 matrices (bus, gen), each [32 n][64 k] bf16.
__global__ void __launch_bounds__(256) k_convw(const float* __restrict__ tWb,
                                               const float* __restrict__ tWg,
                                               const float* __restrict__ roWb,
                                               const float* __restrict__ roWg,
                                               u16* __restrict__ wt,
                                               u16* __restrict__ rot) {
  int t = blockIdx.x * 256 + threadIdx.x;
  int S = gridDim.x * 256;
  for (int i = t; i < 20 * 4096; i += S) {
    int mat = i >> 12, off = i & 4095, n = off >> 6, k = off & 63;
    const float* src = (mat < 10) ? tWb : tWg;
    int tap = (mat < 10) ? mat : mat - 10;
    wt[i] = f2bf(src[(size_t)tap * 4096 + k * 64 + n]);
  }
  for (int i = t; i < 2 * 2048; i += S) {
    int type = i >> 11, off = i & 2047, n = off >> 6, k = off & 63;
    const float* src = type ? roWg : roWb;
    rot[i] = f2bf(src[k * 32 + n]);
  }
}

// ---------------- CSR build: XCD-sliced hist (cached reads, 4-way MLP) ----------------
__global__ void __launch_bounds__(256) k_hist_sl(const int* __restrict__ bbDst,
                                                 const int* __restrict__ gbDst,
                                                 const int* __restrict__ bgDst,
                                                 int* __restrict__ busCnt,
                                                 int* __restrict__ bgCnt) {
  const int g = blockIdx.x & 7;
  const int blk = blockIdx.x >> 3;
  const int nblk = gridDim.x >> 3;
  const int start = blk * 256 + threadIdx.x;
  const int S = nblk * 256;
  int i = start;
  for (; i + 3 * S < NEBB; i += 4 * S) {
    int d0 = bbDst[i], d1 = bbDst[i + S], d2 = bbDst[i + 2 * S], d3 = bbDst[i + 3 * S];
    if ((d0 >> 14) == g) atomicAdd(&busCnt[d0], 1);
    if ((d1 >> 14) == g) atomicAdd(&busCnt[d1], 1);
    if ((d2 >> 14) == g) atomicAdd(&busCnt[d2], 1);
    if ((d3 >> 14) == g) atomicAdd(&busCnt[d3], 1);
  }
  for (; i < NEBB; i += S) {
    int d = bbDst[i];
    if ((d >> 14) == g) atomicAdd(&busCnt[d], 1);
  }
  for (i = start; i < NEGB; i += S) {
    int d = gbDst[i];
    if ((d >> 14) == g) atomicAdd(&busCnt[d], 1);
  }
  for (i = start; i < NEBG; i += S) {
    int d = bgDst[i];
    if ((d >> 12) == g) atomicAdd(&bgCnt[d], 1);
  }
}

__global__ void k_scan1(const int* __restrict__ in, int* __restrict__ out,
                        int* __restrict__ bsums, int n) {
  __shared__ int sh[256];
  int t = threadIdx.x;
  int base = blockIdx.x * 1024 + t * 4;
  int v0 = (base + 0 < n) ? in[base + 0] : 0;
  int v1 = (base + 1 < n) ? in[base + 1] : 0;
  int v2 = (base + 2 < n) ? in[base + 2] : 0;
  int v3 = (base + 3 < n) ? in[base + 3] : 0;
  int t0 = v0, t1 = t0 + v1, t2 = t1 + v2, t3 = t2 + v3;
  sh[t] = t3;
  __syncthreads();
  for (int off = 1; off < 256; off <<= 1) {
    int x = (t >= off) ? sh[t - off] : 0;
    __syncthreads();
    sh[t] += x;
    __syncthreads();
  }
  int excl = (t > 0) ? sh[t - 1] : 0;
  if (base + 0 < n) out[base + 0] = excl;
  if (base + 1 < n) out[base + 1] = excl + t0;
  if (base + 2 < n) out[base + 2] = excl + t1;
  if (base + 3 < n) out[base + 3] = excl + t2;
  if (t == 255) bsums[blockIdx.x] = sh[255];
}

__global__ void k_scan2(int* __restrict__ bsums, int nb) {
  __shared__ int sh[256];
  int t = threadIdx.x;
  int v = (t < nb) ? bsums[t] : 0;
  sh[t] = v;
  __syncthreads();
  for (int off = 1; off < 256; off <<= 1) {
    int x = (t >= off) ? sh[t - off] : 0;
    __syncthreads();
    sh[t] += x;
    __syncthreads();
  }
  int excl = (t > 0) ? sh[t - 1] : 0;
  if (t < nb) bsums[t] = excl;
}

__global__ void k_scan3(int* __restrict__ off, int* __restrict__ cur,
                        const int* __restrict__ bsums, int n, int E) {
  int stride = gridDim.x * blockDim.x;
  for (int i = blockIdx.x * blockDim.x + threadIdx.x; i < n; i += stride) {
    int o = off[i] + bsums[i >> 10];
    off[i] = o;
    cur[i] = o;
  }
  if (blockIdx.x == 0 && threadIdx.x == 0) off[n] = E;
}

// ---------------- CSR fill: XCD-sliced (cached reads, 4-way MLP) ----------------
__global__ void __launch_bounds__(256) k_fill_sl(const int* __restrict__ bbSrc,
                                                 const int* __restrict__ bbDst,
                                                 const int* __restrict__ gbSrc,
                                                 const int* __restrict__ gbDst,
                                                 const int* __restrict__ bgSrc,
                                                 const int* __restrict__ bgDst,
                                                 int* __restrict__ busCur,
                                                 int* __restrict__ bgCur,
                                                 int* __restrict__ busSrt,
                                                 int* __restrict__ bgSrt) {
  const int g = blockIdx.x & 7;
  const int tid = threadIdx.x;
  if (blockIdx.x < 2048) {  // bus-bus edges
    const int blk = blockIdx.x >> 3;
    const int S = 256 * 256;
    int i = blk * 256 + tid;
    for (; i + 3 * S < NEBB; i += 4 * S) {
      int d0 = bbDst[i], d1 = bbDst[i + S], d2 = bbDst[i + 2 * S], d3 = bbDst[i + 3 * S];
      if ((d0 >> 14) == g) { int p = atomicAdd(&busCur[d0], 1); busSrt[p] = bbSrc[i]; }
      if ((d1 >> 14) == g) { int p = atomicAdd(&busCur[d1], 1); busSrt[p] = bbSrc[i + S]; }
      if ((d2 >> 14) == g) { int p = atomicAdd(&busCur[d2], 1); busSrt[p] = bbSrc[i + 2 * S]; }
      if ((d3 >> 14) == g) { int p = atomicAdd(&busCur[d3], 1); busSrt[p] = bbSrc[i + 3 * S]; }
    }
    for (; i < NEBB; i += S) {
      int d = bbDst[i];
      if ((d >> 14) == g) { int p = atomicAdd(&busCur[d], 1); busSrt[p] = bbSrc[i]; }
    }
  } else if (blockIdx.x < 2304) {  // gen->bus edges (src offset +NBUS)
    const int blk = (blockIdx.x - 2048) >> 3;
    const int S = 32 * 256;
    for (int i = blk * 256 + tid; i < NEGB; i += S) {
      int d = gbDst[i];
      if ((d >> 14) == g) { int p = atomicAdd(&busCur[d], 1); busSrt[p] = gbSrc[i] + NBUS; }
    }
  } else {  // bus->gen edges
    const int blk = (blockIdx.x - 2304) >> 3;
    const int S = 32 * 256;
    for (int i = blk * 256 + tid; i < NEBG; i += S) {
      int d = bgDst[i];
      if ((d >> 12) == g) { int p = atomicAdd(&bgCur[d], 1); bgSrt[p] = bgSrc[i]; }
    }
  }
}

// ---------------- merged readin (bus+gen rows) + fused BN-stats ----------------
__global__ void __launch_bounds__(256) k_readin(const float* __restrict__ xbus,
                                                const float* __restrict__ xgen,
                                                const float* __restrict__ Wb,
                                                const float* __restrict__ bb_,
                                                const float* __restrict__ Wg,
                                                const float* __restrict__ bg_,
                                                float* __restrict__ y,
                                                float* __restrict__ stats) {
  __shared__ float WsB[2048];
  __shared__ float WsG[2048];
  __shared__ float shs[4][64];
  __shared__ float shs2[4][64];
  for (int i = threadIdx.x; i < 2048; i += 256) {
    WsB[i] = Wb[i];
    WsG[i] = Wg[i];
  }
  __syncthreads();
  int lane = threadIdx.x & 63;
  int wib = threadIdx.x >> 6;
  float bvB = bb_[lane], bvG = bg_[lane];
  int w = (blockIdx.x * blockDim.x + threadIdx.x) >> 6;
  int nw = (gridDim.x * blockDim.x) >> 6;
  float lsB = 0.f, ls2B = 0.f, lsG = 0.f, ls2G = 0.f;
  for (int g = w; g < NALL; g += nw) {
    bool isBus = g < NBUS;
    const float* xin = isBus ? xbus : xgen;
    int rl = isBus ? g : g - NBUS;
    const float* Ws = isBus ? WsB : WsG;
    float v = xin[(size_t)rl * 32 + (lane & 31)];
    float acc = isBus ? bvB : bvG;
#pragma unroll
    for (int i = 0; i < 32; i++) {
      float xi = __shfl(v, i, 64);
      acc = fmaf(xi, Ws[i * 64 + lane], acc);
    }
    y[(size_t)g * 64 + lane] = acc;
    if (isBus) {
      lsB += acc;
      ls2B = fmaf(acc, acc, ls2B);
    } else {
      lsG += acc;
      ls2G = fmaf(acc, acc, ls2G);
    }
  }
  shs[wib][lane] = lsB;
  shs2[wib][lane] = ls2B;
  __syncthreads();
  if (threadIdx.x < 64) {
    int c = threadIdx.x;
    atomicAdd(&stats[c], shs[0][c] + shs[1][c] + shs[2][c] + shs[3][c]);
  } else if (threadIdx.x < 128) {
    int c = threadIdx.x & 63;
    atomicAdd(&stats[64 + c], shs2[0][c] + shs2[1][c] + shs2[2][c] + shs2[3][c]);
  }
  __syncthreads();
  shs[wib][lane] = lsG;
  shs2[wib][lane] = ls2G;
  __syncthreads();
  if (threadIdx.x < 64) {
    int c = threadIdx.x;
    atomicAdd(&stats[128 + c], shs[0][c] + shs[1][c] + shs[2][c] + shs[3][c]);
  } else if (threadIdx.x < 128) {
    int c = threadIdx.x & 63;
    atomicAdd(&stats[192 + c], shs2[0][c] + shs2[1][c] + shs2[2][c] + shs2[3][c]);
  }
}

// ---------------- BN-finalize + normalize + lrelu + MFMA tap0, 64-row tiles --------------
__global__ void __launch_bounds__(256) k_norm_tap0(float* __restrict__ x,
                                                   u16* __restrict__ c0,
                                                   const float* __restrict__ stats,
                                                   const float* __restrict__ gammaB,
                                                   const float* __restrict__ betaB,
                                                   const float* __restrict__ gammaG,
                                                   const float* __restrict__ betaG,
                                                   const u16* __restrict__ wt,
                                                   const float* __restrict__ tbb,
                                                   const float* __restrict__ tbg,
                                                   int tapIdx) {
  __shared__ u16 yt[64][72];  // padded: row stride 144 B -> 2-way banks (free)
  const int tile = blockIdx.x;
  const bool isBus = tile < NTILE_BUS;
  const int tid = threadIdx.x, lane = tid & 63, wv = tid >> 6;
  int so = isBus ? 0 : 128;
  float invN = isBus ? (1.0f / NBUS) : (1.0f / NGEN);
  float mn = stats[so + lane] * invN;
  float m2 = stats[so + 64 + lane] * invN;
  float rs = rsqrtf(m2 - mn * mn + 1e-5f);
  float scale = (isBus ? gammaB : gammaG)[lane] * rs;
  float shift = (isBus ? betaB : betaG)[lane] - mn * scale;
  unsigned* cu = (unsigned*)c0;
  int rw0 = tile * 64 + wv * 16;
  for (int i = 0; i < 16; i++) {
    int row = rw0 + i;
    float xv = x[(size_t)row * 64 + lane];
    float y = fmaf(xv, scale, shift);
    y = (y >= 0.f) ? y : 0.01f * y;
    float ypair = __shfl(y, lane ^ 1, 64);
    if ((lane & 1) == 0) {
      unsigned pk = pack2bf(y, ypair);
      cu[(size_t)row * 32 + (lane >> 1)] = pk;  // gather source (row-major bf16)
      *(unsigned*)&yt[wv * 16 + i][lane] = pk;
    }
  }
  __syncthreads();
  const int m = lane & 15, kq = lane >> 4;
  const u16* wrow = wt + (size_t)((isBus ? 0 : 10) + tapIdx) * 4096;
  const float* bbase = isBus ? tbb : tbg;
  int lr = wv * 16 + m;
  s16x8 a0 = *(const s16x8*)&yt[lr][kq * 8];
  s16x8 a1 = *(const s16x8*)&yt[lr][32 + kq * 8];
  f32x4 acc[4];
#pragma unroll
  for (int cb = 0; cb < 4; cb++) acc[cb] = (f32x4){0.f, 0.f, 0.f, 0.f};
#pragma unroll
  for (int cb = 0; cb < 4; cb++) {
    const u16* wp = wrow + (cb * 16 + m) * 64 + kq * 8;
    s16x8 b0 = *(const s16x8*)&wp[0];
    s16x8 b1 = *(const s16x8*)&wp[32];
    acc[cb] = __builtin_amdgcn_mfma_f32_16x16x32_bf16(a0, b0, acc[cb], 0, 0, 0);
    acc[cb] = __builtin_amdgcn_mfma_f32_16x16x32_bf16(a1, b1, acc[cb], 0, 0, 0);
  }
  const int orow0 = tile * 64 + wv * 16 + kq * 4;
#pragma unroll
  for (int cb = 0; cb < 4; cb++) {
    int col = cb * 16 + m;
    float bsv = bbase[(size_t)tapIdx * 64 + col];
#pragma unroll
    for (int i = 0; i < 4; i++) {
      size_t idx = (size_t)(orow0 + i) * 64 + col;
      x[idx] += acc[cb][i] + bsv;
    }
  }
}

// ---------------- phase A: CSR gather, row-major bf16, 8 lanes/row, uint4 loads ----------
__global__ void __launch_bounds__(256) k_gather(const int* __restrict__ busOff,
                                                const int* __restrict__ busSrt,
                                                const int* __restrict__ bgOff,
                                                const int* __restrict__ bgSrt,
                                                const u16* __restrict__ src,
                                                u16* __restrict__ dst) {
  const int lane = threadIdx.x & 63;
  const int wv = threadIdx.x >> 6;
  const int grp = lane >> 3;  // row slot within wave (0..7)
  const int sub = lane & 7;   // 16 B chunk within the 128 B row
  const unsigned* s32 = (const unsigned*)src;
  unsigned* d32 = (unsigned*)dst;
  int rowBase = (blockIdx.x * 4 + wv) * 8;
  const int rstride = gridDim.x * 32;
  for (int row0 = rowBase; row0 < NALL; row0 += rstride) {
    int row = row0 + grp;
    int beg, end;
    const int* srt;
    if (row < NBUS) {
      beg = busOff[row];
      end = busOff[row + 1];
      srt = busSrt;
    } else {
      beg = bgOff[row - NBUS];
      end = bgOff[row - NBUS + 1];
      srt = bgSrt;
    }
    f32x2 a0 = {0.f, 0.f}, a1 = {0.f, 0.f}, a2 = {0.f, 0.f}, a3 = {0.f, 0.f};
    for (int e = beg; e < end; e += 8) {
      uint4 v[8];
      int last = end - 1;
#pragma unroll
      for (int j = 0; j < 8; j++) {
        int idx = e + j;
        bool ok = idx < end;
        if (!ok) idx = last;
        int s = srt[idx];
        uint4 vv = *(const uint4*)&s32[(size_t)s * 32 + sub * 4];
        if (!ok) { vv.x = 0; vv.y = 0; vv.z = 0; vv.w = 0; }
        v[j] = vv;
      }
#pragma unroll
      for (int j = 0; j < 8; j++) {
        a0 += bf2x2(v[j].x);
        a1 += bf2x2(v[j].y);
        a2 += bf2x2(v[j].z);
        a3 += bf2x2(v[j].w);
      }
    }
    uint4 o;
    o.x = pack2bf(a0.x, a0.y);
    o.y = pack2bf(a1.x, a1.y);
    o.z = pack2bf(a2.x, a2.y);
    o.w = pack2bf(a3.x, a3.y);
    *(uint4*)&d32[(size_t)row * 32 + sub * 4] = o;
  }
}

// ---------------- phase B: TWO fused MFMA tap GEMMs per dispatch, 64-row tiles -----------
__global__ void __launch_bounds__(256) k_tap2(const u16* __restrict__ cA,
                                              const u16* __restrict__ cB,
                                              float* __restrict__ x,
                                              const u16* __restrict__ wt,
                                              const float* __restrict__ tbb,
                                              const float* __restrict__ tbg,
                                              int idxA, int idxB,
                                              float* __restrict__ stats) {
  __shared__ float sst[128];
  const int tile = blockIdx.x;
  const bool isBus = tile < NTILE_BUS;
  const int row0 = tile * 64;
  const int tid = threadIdx.x, lane = tid & 63, wv = tid >> 6;
  const int m = lane & 15, kq = lane >> 4;
  const int arow = row0 + wv * 16 + m;
  const float* bbase = isBus ? tbb : tbg;
  const u16* wbase = wt + (size_t)(isBus ? 0 : 10) * 4096;
  f32x4 acc[4];
#pragma unroll
  for (int cb = 0; cb < 4; cb++) acc[cb] = (f32x4){0.f, 0.f, 0.f, 0.f};
  const u16* cs[2] = {cA, cB};
  const int idxs[2] = {idxA, idxB};
#pragma unroll
  for (int s = 0; s < 2; s++) {
    const u16* c = cs[s];
    s16x8 a0 = *(const s16x8*)&c[(size_t)arow * 64 + kq * 8];
    s16x8 a1 = *(const s16x8*)&c[(size_t)arow * 64 + 32 + kq * 8];
    const u16* wrow = wbase + (size_t)idxs[s] * 4096;
#pragma unroll
    for (int cb = 0; cb < 4; cb++) {
      const u16* wp = wrow + (cb * 16 + m) * 64 + kq * 8;
      s16x8 b0 = *(const s16x8*)&wp[0];
      s16x8 b1 = *(const s16x8*)&wp[32];
      acc[cb] = __builtin_amdgcn_mfma_f32_16x16x32_bf16(a0, b0, acc[cb], 0, 0, 0);
      acc[cb] = __builtin_amdgcn_mfma_f32_16x16x32_bf16(a1, b1, acc[cb], 0, 0, 0);
    }
  }
  if (stats) {
    if (tid < 128) sst[tid] = 0.f;
    __syncthreads();
  }
  const int orow0 = row0 + wv * 16 + kq * 4;
#pragma unroll
  for (int cb = 0; cb < 4; cb++) {
    int col = cb * 16 + m;
    float bsv = bbase[(size_t)idxA * 64 + col] + bbase[(size_t)idxB * 64 + col];
    float s1 = 0.f, s2 = 0.f;
#pragma unroll
    for (int i = 0; i < 4; i++) {
      size_t idx = (size_t)(orow0 + i) * 64 + col;
      float xo = x[idx] + acc[cb][i] + bsv;
      x[idx] = xo;
      s1 += xo;
      s2 = fmaf(xo, xo, s2);
    }
    if (stats) {
      atomicAdd(&sst[col], s1);
      atomicAdd(&sst[64 + col], s2);
    }
  }
  if (stats) {
    __syncthreads();
    if (tid < 64) {
      atomicAdd(&stats[(isBus ? 0 : 128) + tid], sst[tid]);
      atomicAdd(&stats[(isBus ? 0 : 128) + 64 + tid], sst[64 + tid]);
    }
  }
}

// ---------------- MFMA readout: out = x@Wro + b ----------------
__global__ void __launch_bounds__(256) k_readout(const float* __restrict__ x,
                                                 const u16* __restrict__ rot,
                                                 const float* __restrict__ robb,
                                                 const float* __restrict__ robg,
                                                 float* __restrict__ out) {
  const int tile = blockIdx.x;
  const bool isBus = tile < NTILE_BUS;
  const int tid = threadIdx.x, lane = tid & 63, wv = tid >> 6;
  const int m = lane & 15, kq = lane >> 4;
  const int arow = tile * 64 + wv * 16 + m;
  const float* xp = &x[(size_t)arow * 64 + kq * 8];
  s16x8 a0, a1;
#pragma unroll
  for (int j = 0; j < 8; j++) a0[j] = (short)f2bf(xp[j]);
#pragma unroll
  for (int j = 0; j < 8; j++) a1[j] = (short)f2bf(xp[32 + j]);
  const u16* rbase = rot + (size_t)(isBus ? 0 : 1) * 2048;
  f32x4 acc[2];
  acc[0] = (f32x4){0.f, 0.f, 0.f, 0.f};
  acc[1] = (f32x4){0.f, 0.f, 0.f, 0.f};
#pragma unroll
  for (int cb = 0; cb < 2; cb++) {
    const u16* wp = rbase + (cb * 16 + m) * 64 + kq * 8;
    s16x8 b0 = *(const s16x8*)&wp[0];
    s16x8 b1 = *(const s16x8*)&wp[32];
    acc[cb] = __builtin_amdgcn_mfma_f32_16x16x32_bf16(a0, b0, acc[cb], 0, 0, 0);
    acc[cb] = __builtin_amdgcn_mfma_f32_16x16x32_bf16(a1, b1, acc[cb], 0, 0, 0);
  }
  const float* bb = isBus ? robb : robg;
  const int orow0 = tile * 64 + wv * 16 + kq * 4;
#pragma unroll
  for (int cb = 0; cb < 2; cb++) {
    int col = cb * 16 + m;
    float bv = bb[col];
#pragma unroll
    for (int i = 0; i < 4; i++)
      out[(size_t)(orow0 + i) * 32 + col] = acc[cb][i] + bv;
  }
}

extern "C" void kernel_launch(void* const* d_in, const int* in_sizes, int n_in,
                              void* d_out, int out_size, void* d_ws, size_t ws_size,
                              hipStream_t stream) {
  const float* x_bus = (const float*)d_in[0];
  const float* x_gen = (const float*)d_in[1];
  const float* riWb = (const float*)d_in[2];
  const float* ribb = (const float*)d_in[3];
  const float* riWg = (const float*)d_in[4];
  const float* ribg = (const float*)d_in[5];
  const float* bng_b = (const float*)d_in[6];
  const float* bnb_b = (const float*)d_in[7];
  const float* bng_g = (const float*)d_in[8];
  const float* bnb_g = (const float*)d_in[9];
  const float* tWb = (const float*)d_in[10];
  const float* tbb = (const float*)d_in[11];
  const float* tWg = (const float*)d_in[12];
  const float* tbg = (const float*)d_in[13];
  const float* roWb = (const float*)d_in[14];
  const float* robb = (const float*)d_in[15];
  const float* roWg = (const float*)d_in[16];
  const float* robg = (const float*)d_in[17];
  const int* ebb = (const int*)d_in[18];
  const int* gb_src = (const int*)d_in[19];
  const int* gb_dst = (const int*)d_in[20];
  const int* bg_src = (const int*)d_in[21];
  const int* bg_dst = (const int*)d_in[22];
  const int* bb_src = ebb;
  const int* bb_dst = ebb + NEBB;

  // ---- workspace layout (256B aligned segments) ----
  char* p = (char*)d_ws;
  auto take = [&](size_t bytes) -> void* {
    void* r = (void*)p;
    p += (bytes + 255) & ~(size_t)255;
    return r;
  };
  float* x = (float*)take((size_t)NALL * 64 * 4);  // bus rows [0,NBUS), gen rows after
  u16* b0 = (u16*)take((size_t)NALL * 64 * 2);     // row-major bf16 shift-state buffers
  u16* b1 = (u16*)take((size_t)NALL * 64 * 2);
  u16* b2 = (u16*)take((size_t)NALL * 64 * 2);
  int* bus_off = (int*)take((size_t)(NBUS + 1) * 4);
  int* bus_srt = (int*)take((size_t)NEBUS * 4);
  int* bg_off = (int*)take((size_t)(NGEN + 1) * 4);
  int* bg_srt = (int*)take((size_t)NEBG * 4);
  int* bsums = (int*)take(256 * 4);
  u16* wt = (u16*)take((size_t)20 * 4096 * 2);  // bf16 [n][k] tap weights
  u16* rot = (u16*)take((size_t)2 * 2048 * 2);  // bf16 [n][k] readout weights
  // zero-initialized group (contiguous -> single memset)
  int* bus_cur = (int*)take((size_t)NBUS * 4);
  int* bg_cur = (int*)take((size_t)NGEN * 4);
  float* stats0 = (float*)take(256 * 4);  // [bus s, bus s2, gen s, gen s2]
  float* stats1 = (float*)take(256 * 4);
  size_t zlen = (char*)p - (char*)bus_cur;
  if ((size_t)(p - (char*)d_ws) > ws_size) return;  // ws too small -> visible validation failure

  // ---- weight prep + CSR build ----
  hipMemsetAsync(bus_cur, 0, zlen, stream);
  k_convw<<<320, 256, 0, stream>>>(tWb, tWg, roWb, roWg, wt, rot);

  k_hist_sl<<<2048, 256, 0, stream>>>(bb_dst, gb_dst, bg_dst, bus_cur, bg_cur);

  k_scan1<<<128, 256, 0, stream>>>(bus_cur, bus_off, bsums, NBUS);
  k_scan2<<<1, 256, 0, stream>>>(bsums, 128);
  k_scan3<<<512, 256, 0, stream>>>(bus_off, bus_cur, bsums, NBUS, NEBUS);

  k_scan1<<<32, 256, 0, stream>>>(bg_cur, bg_off, bsums, NGEN);
  k_scan2<<<1, 256, 0, stream>>>(bsums, 32);
  k_scan3<<<128, 256, 0, stream>>>(bg_off, bg_cur, bsums, NGEN, NEBG);

  k_fill_sl<<<2560, 256, 0, stream>>>(bb_src, bb_dst, gb_src, gb_dst, bg_src, bg_dst,
                                      bus_cur, bg_cur, bus_srt, bg_srt);

  // ---- readin (+ layer-0 BN stats) ----
  k_readin<<<5120, 256, 0, stream>>>(x_bus, x_gen, riWb, ribb, riWg, ribg, x, stats0);

  // ---- residual blocks: tap0 -> A,A,B2 -> A,A,B2 ----
  for (int l = 0; l < 2; l++) {
    float* statsL = (l == 0) ? stats0 : stats1;
    k_norm_tap0<<<NTILE, 256, 0, stream>>>(x, b0, statsL,
                                           bng_b + l * 64, bnb_b + l * 64,
                                           bng_g + l * 64, bnb_g + l * 64,
                                           wt, tbb, tbg, l * 5);
    k_gather<<<2560, 256, 0, stream>>>(bus_off, bus_srt, bg_off, bg_srt, b0, b1);
    k_gather<<<2560, 256, 0, stream>>>(bus_off, bus_srt, bg_off, bg_srt, b1, b2);
    k_tap2<<<NTILE, 256, 0, stream>>>(b1, b2, x, wt, tbb, tbg,
                                      l * 5 + 1, l * 5 + 2, (float*)nullptr);
    k_gather<<<2560, 256, 0, stream>>>(bus_off, bus_srt, bg_off, bg_srt, b2, b0);
    k_gather<<<2560, 256, 0, stream>>>(bus_off, bus_srt, bg_off, bg_srt, b0, b1);
    k_tap2<<<NTILE, 256, 0, stream>>>(b0, b1, x, wt, tbb, tbg,
                                      l * 5 + 3, l * 5 + 4,
                                      (l == 0) ? stats1 : (float*)nullptr);
  }

  // ---- readout ----
  k_readout<<<NTILE, 256, 0, stream>>>(x, rot, robb, robg, (float*)d_out);
}

// Round 11
// 839.352 us; speedup vs baseline: 3.4658x; 1.0938x over previous
//
#include <hip/hip_runtime.h>

#define NBUS 131072
#define NGEN 32768
#define NALL (NBUS + NGEN)
#define NEBB 2097152
#define NEGB 65536
#define NEBG 65536
#define NEBUS (NEBB + NEGB)   // merged bus-dest CSR (bb + gb)
#define NTILE (NALL / 64)     // 2560
#define NTILE_BUS (NBUS / 64) // 2048

typedef float f32x2 __attribute__((ext_vector_type(2)));
typedef float f32x4 __attribute__((ext_vector_type(4)));
typedef short s16x8 __attribute__((ext_vector_type(8)));
typedef unsigned short u16;

__device__ inline f32x2 bf2x2(unsigned v) {  // unpack 2 bf16 (packed u32) -> 2 f32
  f32x2 r;
  r.x = __builtin_bit_cast(float, v << 16);
  r.y = __builtin_bit_cast(float, v & 0xFFFF0000u);
  return r;
}
__device__ inline u16 f2bf(float f) {  // round-to-nearest-even
  unsigned u = __builtin_bit_cast(unsigned, f);
  unsigned r = u + 0x7FFFu + ((u >> 16) & 1u);
  return (u16)(r >> 16);
}
__device__ inline unsigned pack2bf(float a, float b) {
  return (unsigned)f2bf(a) | ((unsigned)f2bf(b) << 16);
}

// ---------------- weight prep: bf16 transposed [n][k] layouts ----------------
// wt: 20 matrices (bus taps 0..9, gen taps 10..19), each [64 n][64 k] bf16.
// rot: 2 matrices (bus, gen), each [32 n][64 k] bf16.
// riwt: 2 matrices (bus, gen), each [64 n][32 k] bf16 (readin).
__global__ void __launch_bounds__(256) k_convw(const float* __restrict__ tWb,
                                               const float* __restrict__ tWg,
                                               const float* __restrict__ roWb,
                                               const float* __restrict__ roWg,
                                               const float* __restrict__ riWb,
                                               const float* __restrict__ riWg,
                                               u16* __restrict__ wt,
                                               u16* __restrict__ rot,
                                               u16* __restrict__ riwt) {
  int t = blockIdx.x * 256 + threadIdx.x;
  int S = gridDim.x * 256;
  for (int i = t; i < 20 * 4096; i += S) {
    int mat = i >> 12, off = i & 4095, n = off >> 6, k = off & 63;
    const float* src = (mat < 10) ? tWb : tWg;
    int tap = (mat < 10) ? mat : mat - 10;
    wt[i] = f2bf(src[(size_t)tap * 4096 + k * 64 + n]);
  }
  for (int i = t; i < 2 * 2048; i += S) {
    int type = i >> 11, off = i & 2047, n = off >> 6, k = off & 63;
    const float* src = type ? roWg : roWb;
    rot[i] = f2bf(src[k * 32 + n]);
  }
  for (int i = t; i < 2 * 2048; i += S) {
    int type = i >> 11, off = i & 2047, n = off >> 5, k = off & 31;
    const float* src = type ? riWg : riWb;
    riwt[i] = f2bf(src[k * 64 + n]);
  }
}

// ---------------- CSR build: XCD-sliced hist (cached reads, 4-way MLP) ----------------
__global__ void __launch_bounds__(256) k_hist_sl(const int* __restrict__ bbDst,
                                                 const int* __restrict__ gbDst,
                                                 const int* __restrict__ bgDst,
                                                 int* __restrict__ busCnt,
                                                 int* __restrict__ bgCnt) {
  const int g = blockIdx.x & 7;
  const int blk = blockIdx.x >> 3;
  const int nblk = gridDim.x >> 3;
  const int start = blk * 256 + threadIdx.x;
  const int S = nblk * 256;
  int i = start;
  for (; i + 3 * S < NEBB; i += 4 * S) {
    int d0 = bbDst[i], d1 = bbDst[i + S], d2 = bbDst[i + 2 * S], d3 = bbDst[i + 3 * S];
    if ((d0 >> 14) == g) atomicAdd(&busCnt[d0], 1);
    if ((d1 >> 14) == g) atomicAdd(&busCnt[d1], 1);
    if ((d2 >> 14) == g) atomicAdd(&busCnt[d2], 1);
    if ((d3 >> 14) == g) atomicAdd(&busCnt[d3], 1);
  }
  for (; i < NEBB; i += S) {
    int d = bbDst[i];
    if ((d >> 14) == g) atomicAdd(&busCnt[d], 1);
  }
  for (i = start; i < NEGB; i += S) {
    int d = gbDst[i];
    if ((d >> 14) == g) atomicAdd(&busCnt[d], 1);
  }
  for (i = start; i < NEBG; i += S) {
    int d = bgDst[i];
    if ((d >> 12) == g) atomicAdd(&bgCnt[d], 1);
  }
}

__global__ void k_scan1(const int* __restrict__ in, int* __restrict__ out,
                        int* __restrict__ bsums, int n) {
  __shared__ int sh[256];
  int t = threadIdx.x;
  int base = blockIdx.x * 1024 + t * 4;
  int v0 = (base + 0 < n) ? in[base + 0] : 0;
  int v1 = (base + 1 < n) ? in[base + 1] : 0;
  int v2 = (base + 2 < n) ? in[base + 2] : 0;
  int v3 = (base + 3 < n) ? in[base + 3] : 0;
  int t0 = v0, t1 = t0 + v1, t2 = t1 + v2, t3 = t2 + v3;
  sh[t] = t3;
  __syncthreads();
  for (int off = 1; off < 256; off <<= 1) {
    int x = (t >= off) ? sh[t - off] : 0;
    __syncthreads();
    sh[t] += x;
    __syncthreads();
  }
  int excl = (t > 0) ? sh[t - 1] : 0;
  if (base + 0 < n) out[base + 0] = excl;
  if (base + 1 < n) out[base + 1] = excl + t0;
  if (base + 2 < n) out[base + 2] = excl + t1;
  if (base + 3 < n) out[base + 3] = excl + t2;
  if (t == 255) bsums[blockIdx.x] = sh[255];
}

__global__ void k_scan2(int* __restrict__ bsums, int nb) {
  __shared__ int sh[256];
  int t = threadIdx.x;
  int v = (t < nb) ? bsums[t] : 0;
  sh[t] = v;
  __syncthreads();
  for (int off = 1; off < 256; off <<= 1) {
    int x = (t >= off) ? sh[t - off] : 0;
    __syncthreads();
    sh[t] += x;
    __syncthreads();
  }
  int excl = (t > 0) ? sh[t - 1] : 0;
  if (t < nb) bsums[t] = excl;
}

__global__ void k_scan3(int* __restrict__ off, int* __restrict__ cur,
                        const int* __restrict__ bsums, int n, int E) {
  int stride = gridDim.x * blockDim.x;
  for (int i = blockIdx.x * blockDim.x + threadIdx.x; i < n; i += stride) {
    int o = off[i] + bsums[i >> 10];
    off[i] = o;
    cur[i] = o;
  }
  if (blockIdx.x == 0 && threadIdx.x == 0) off[n] = E;
}

// ---------------- CSR fill: XCD-sliced (cached reads, 4-way MLP) ----------------
__global__ void __launch_bounds__(256) k_fill_sl(const int* __restrict__ bbSrc,
                                                 const int* __restrict__ bbDst,
                                                 const int* __restrict__ gbSrc,
                                                 const int* __restrict__ gbDst,
                                                 const int* __restrict__ bgSrc,
                                                 const int* __restrict__ bgDst,
                                                 int* __restrict__ busCur,
                                                 int* __restrict__ bgCur,
                                                 int* __restrict__ busSrt,
                                                 int* __restrict__ bgSrt) {
  const int g = blockIdx.x & 7;
  const int tid = threadIdx.x;
  if (blockIdx.x < 2048) {  // bus-bus edges
    const int blk = blockIdx.x >> 3;
    const int S = 256 * 256;
    int i = blk * 256 + tid;
    for (; i + 3 * S < NEBB; i += 4 * S) {
      int d0 = bbDst[i], d1 = bbDst[i + S], d2 = bbDst[i + 2 * S], d3 = bbDst[i + 3 * S];
      if ((d0 >> 14) == g) { int p = atomicAdd(&busCur[d0], 1); busSrt[p] = bbSrc[i]; }
      if ((d1 >> 14) == g) { int p = atomicAdd(&busCur[d1], 1); busSrt[p] = bbSrc[i + S]; }
      if ((d2 >> 14) == g) { int p = atomicAdd(&busCur[d2], 1); busSrt[p] = bbSrc[i + 2 * S]; }
      if ((d3 >> 14) == g) { int p = atomicAdd(&busCur[d3], 1); busSrt[p] = bbSrc[i + 3 * S]; }
    }
    for (; i < NEBB; i += S) {
      int d = bbDst[i];
      if ((d >> 14) == g) { int p = atomicAdd(&busCur[d], 1); busSrt[p] = bbSrc[i]; }
    }
  } else if (blockIdx.x < 2304) {  // gen->bus edges (src offset +NBUS)
    const int blk = (blockIdx.x - 2048) >> 3;
    const int S = 32 * 256;
    for (int i = blk * 256 + tid; i < NEGB; i += S) {
      int d = gbDst[i];
      if ((d >> 14) == g) { int p = atomicAdd(&busCur[d], 1); busSrt[p] = gbSrc[i] + NBUS; }
    }
  } else {  // bus->gen edges
    const int blk = (blockIdx.x - 2304) >> 3;
    const int S = 32 * 256;
    for (int i = blk * 256 + tid; i < NEBG; i += S) {
      int d = bgDst[i];
      if ((d >> 12) == g) { int p = atomicAdd(&bgCur[d], 1); bgSrt[p] = bgSrc[i]; }
    }
  }
}

// ---------------- MFMA readin: y = x_in @ W_ri + b (+ fused BN stats), 64-row tiles ------
__global__ void __launch_bounds__(256) k_readin(const float* __restrict__ xbus,
                                                const float* __restrict__ xgen,
                                                const u16* __restrict__ riwt,
                                                const float* __restrict__ bb_,
                                                const float* __restrict__ bg_,
                                                float* __restrict__ y,
                                                float* __restrict__ stats) {
  __shared__ float sst[128];
  const int tile = blockIdx.x;
  const bool isBus = tile < NTILE_BUS;
  const int tid = threadIdx.x, lane = tid & 63, wv = tid >> 6;
  const int m = lane & 15, kq = lane >> 4;
  const int grow = tile * 64 + wv * 16 + m;
  const float* xp = isBus ? &xbus[(size_t)grow * 32] : &xgen[(size_t)(grow - NBUS) * 32];
  s16x8 a;
#pragma unroll
  for (int j = 0; j < 8; j++) a[j] = (short)f2bf(xp[kq * 8 + j]);
  const u16* rb = riwt + (size_t)(isBus ? 0 : 1) * 2048;
  const float* bb = isBus ? bb_ : bg_;
  f32x4 acc[4];
#pragma unroll
  for (int cb = 0; cb < 4; cb++) {
    acc[cb] = (f32x4){0.f, 0.f, 0.f, 0.f};
    const u16* wp = rb + (cb * 16 + m) * 32 + kq * 8;
    s16x8 b = *(const s16x8*)wp;
    acc[cb] = __builtin_amdgcn_mfma_f32_16x16x32_bf16(a, b, acc[cb], 0, 0, 0);
  }
  if (tid < 128) sst[tid] = 0.f;
  __syncthreads();
  const int orow0 = tile * 64 + wv * 16 + kq * 4;
#pragma unroll
  for (int cb = 0; cb < 4; cb++) {
    int col = cb * 16 + m;
    float bv = bb[col];
    float s1 = 0.f, s2 = 0.f;
#pragma unroll
    for (int i = 0; i < 4; i++) {
      float yo = acc[cb][i] + bv;
      y[(size_t)(orow0 + i) * 64 + col] = yo;
      s1 += yo;
      s2 = fmaf(yo, yo, s2);
    }
    atomicAdd(&sst[col], s1);
    atomicAdd(&sst[64 + col], s2);
  }
  __syncthreads();
  if (tid < 64) {
    atomicAdd(&stats[(isBus ? 0 : 128) + tid], sst[tid]);
    atomicAdd(&stats[(isBus ? 0 : 128) + 64 + tid], sst[64 + tid]);
  }
}

// ---------------- BN-finalize + normalize + lrelu + MFMA tap0, 64-row tiles --------------
__global__ void __launch_bounds__(256) k_norm_tap0(float* __restrict__ x,
                                                   u16* __restrict__ c0,
                                                   const float* __restrict__ stats,
                                                   const float* __restrict__ gammaB,
                                                   const float* __restrict__ betaB,
                                                   const float* __restrict__ gammaG,
                                                   const float* __restrict__ betaG,
                                                   const u16* __restrict__ wt,
                                                   const float* __restrict__ tbb,
                                                   const float* __restrict__ tbg,
                                                   int tapIdx) {
  __shared__ u16 yt[64][72];  // padded: row stride 144 B -> 2-way banks (free)
  const int tile = blockIdx.x;
  const bool isBus = tile < NTILE_BUS;
  const int tid = threadIdx.x, lane = tid & 63, wv = tid >> 6;
  int so = isBus ? 0 : 128;
  float invN = isBus ? (1.0f / NBUS) : (1.0f / NGEN);
  float mn = stats[so + lane] * invN;
  float m2 = stats[so + 64 + lane] * invN;
  float rs = rsqrtf(m2 - mn * mn + 1e-5f);
  float scale = (isBus ? gammaB : gammaG)[lane] * rs;
  float shift = (isBus ? betaB : betaG)[lane] - mn * scale;
  unsigned* cu = (unsigned*)c0;
  int rw0 = tile * 64 + wv * 16;
  for (int i = 0; i < 16; i++) {
    int row = rw0 + i;
    float xv = x[(size_t)row * 64 + lane];
    float y = fmaf(xv, scale, shift);
    y = (y >= 0.f) ? y : 0.01f * y;
    float ypair = __shfl(y, lane ^ 1, 64);
    if ((lane & 1) == 0) {
      unsigned pk = pack2bf(y, ypair);
      cu[(size_t)row * 32 + (lane >> 1)] = pk;  // gather source (row-major bf16)
      *(unsigned*)&yt[wv * 16 + i][lane] = pk;
    }
  }
  __syncthreads();
  const int m = lane & 15, kq = lane >> 4;
  const u16* wrow = wt + (size_t)((isBus ? 0 : 10) + tapIdx) * 4096;
  const float* bbase = isBus ? tbb : tbg;
  int lr = wv * 16 + m;
  s16x8 a0 = *(const s16x8*)&yt[lr][kq * 8];
  s16x8 a1 = *(const s16x8*)&yt[lr][32 + kq * 8];
  f32x4 acc[4];
#pragma unroll
  for (int cb = 0; cb < 4; cb++) acc[cb] = (f32x4){0.f, 0.f, 0.f, 0.f};
#pragma unroll
  for (int cb = 0; cb < 4; cb++) {
    const u16* wp = wrow + (cb * 16 + m) * 64 + kq * 8;
    s16x8 b0 = *(const s16x8*)&wp[0];
    s16x8 b1 = *(const s16x8*)&wp[32];
    acc[cb] = __builtin_amdgcn_mfma_f32_16x16x32_bf16(a0, b0, acc[cb], 0, 0, 0);
    acc[cb] = __builtin_amdgcn_mfma_f32_16x16x32_bf16(a1, b1, acc[cb], 0, 0, 0);
  }
  const int orow0 = tile * 64 + wv * 16 + kq * 4;
#pragma unroll
  for (int cb = 0; cb < 4; cb++) {
    int col = cb * 16 + m;
    float bsv = bbase[(size_t)tapIdx * 64 + col];
#pragma unroll
    for (int i = 0; i < 4; i++) {
      size_t idx = (size_t)(orow0 + i) * 64 + col;
      x[idx] += acc[cb][i] + bsv;
    }
  }
}

// ---------------- phase A: CSR gather, row-major bf16, 8 lanes/row, uint4 loads ----------
__global__ void __launch_bounds__(256) k_gather(const int* __restrict__ busOff,
                                                const int* __restrict__ busSrt,
                                                const int* __restrict__ bgOff,
                                                const int* __restrict__ bgSrt,
                                                const u16* __restrict__ src,
                                                u16* __restrict__ dst) {
  const int lane = threadIdx.x & 63;
  const int wv = threadIdx.x >> 6;
  const int grp = lane >> 3;  // row slot within wave (0..7)
  const int sub = lane & 7;   // 16 B chunk within the 128 B row
  const unsigned* s32 = (const unsigned*)src;
  unsigned* d32 = (unsigned*)dst;
  int rowBase = (blockIdx.x * 4 + wv) * 8;
  const int rstride = gridDim.x * 32;
  for (int row0 = rowBase; row0 < NALL; row0 += rstride) {
    int row = row0 + grp;
    int beg, end;
    const int* srt;
    if (row < NBUS) {
      beg = busOff[row];
      end = busOff[row + 1];
      srt = busSrt;
    } else {
      beg = bgOff[row - NBUS];
      end = bgOff[row - NBUS + 1];
      srt = bgSrt;
    }
    f32x2 a0 = {0.f, 0.f}, a1 = {0.f, 0.f}, a2 = {0.f, 0.f}, a3 = {0.f, 0.f};
    for (int e = beg; e < end; e += 8) {
      uint4 v[8];
      int last = end - 1;
#pragma unroll
      for (int j = 0; j < 8; j++) {
        int idx = e + j;
        bool ok = idx < end;
        if (!ok) idx = last;
        int s = srt[idx];
        uint4 vv = *(const uint4*)&s32[(size_t)s * 32 + sub * 4];
        if (!ok) { vv.x = 0; vv.y = 0; vv.z = 0; vv.w = 0; }
        v[j] = vv;
      }
#pragma unroll
      for (int j = 0; j < 8; j++) {
        a0 += bf2x2(v[j].x);
        a1 += bf2x2(v[j].y);
        a2 += bf2x2(v[j].z);
        a3 += bf2x2(v[j].w);
      }
    }
    uint4 o;
    o.x = pack2bf(a0.x, a0.y);
    o.y = pack2bf(a1.x, a1.y);
    o.z = pack2bf(a2.x, a2.y);
    o.w = pack2bf(a3.x, a3.y);
    *(uint4*)&d32[(size_t)row * 32 + sub * 4] = o;
  }
}

// ---------------- phase B: TWO fused MFMA tap GEMMs per dispatch, 64-row tiles -----------
__global__ void __launch_bounds__(256) k_tap2(const u16* __restrict__ cA,
                                              const u16* __restrict__ cB,
                                              float* __restrict__ x,
                                              const u16* __restrict__ wt,
                                              const float* __restrict__ tbb,
                                              const float* __restrict__ tbg,
                                              int idxA, int idxB,
                                              float* __restrict__ stats) {
  __shared__ float sst[128];
  const int tile = blockIdx.x;
  const bool isBus = tile < NTILE_BUS;
  const int row0 = tile * 64;
  const int tid = threadIdx.x, lane = tid & 63, wv = tid >> 6;
  const int m = lane & 15, kq = lane >> 4;
  const int arow = row0 + wv * 16 + m;
  const float* bbase = isBus ? tbb : tbg;
  const u16* wbase = wt + (size_t)(isBus ? 0 : 10) * 4096;
  f32x4 acc[4];
#pragma unroll
  for (int cb = 0; cb < 4; cb++) acc[cb] = (f32x4){0.f, 0.f, 0.f, 0.f};
  const u16* cs[2] = {cA, cB};
  const int idxs[2] = {idxA, idxB};
#pragma unroll
  for (int s = 0; s < 2; s++) {
    const u16* c = cs[s];
    s16x8 a0 = *(const s16x8*)&c[(size_t)arow * 64 + kq * 8];
    s16x8 a1 = *(const s16x8*)&c[(size_t)arow * 64 + 32 + kq * 8];
    const u16* wrow = wbase + (size_t)idxs[s] * 4096;
#pragma unroll
    for (int cb = 0; cb < 4; cb++) {
      const u16* wp = wrow + (cb * 16 + m) * 64 + kq * 8;
      s16x8 b0 = *(const s16x8*)&wp[0];
      s16x8 b1 = *(const s16x8*)&wp[32];
      acc[cb] = __builtin_amdgcn_mfma_f32_16x16x32_bf16(a0, b0, acc[cb], 0, 0, 0);
      acc[cb] = __builtin_amdgcn_mfma_f32_16x16x32_bf16(a1, b1, acc[cb], 0, 0, 0);
    }
  }
  if (stats) {
    if (tid < 128) sst[tid] = 0.f;
    __syncthreads();
  }
  const int orow0 = row0 + wv * 16 + kq * 4;
#pragma unroll
  for (int cb = 0; cb < 4; cb++) {
    int col = cb * 16 + m;
    float bsv = bbase[(size_t)idxA * 64 + col] + bbase[(size_t)idxB * 64 + col];
    float s1 = 0.f, s2 = 0.f;
#pragma unroll
    for (int i = 0; i < 4; i++) {
      size_t idx = (size_t)(orow0 + i) * 64 + col;
      float xo = x[idx] + acc[cb][i] + bsv;
      x[idx] = xo;
      s1 += xo;
      s2 = fmaf(xo, xo, s2);
    }
    if (stats) {
      atomicAdd(&sst[col], s1);
      atomicAdd(&sst[64 + col], s2);
    }
  }
  if (stats) {
    __syncthreads();
    if (tid < 64) {
      atomicAdd(&stats[(isBus ? 0 : 128) + tid], sst[tid]);
      atomicAdd(&stats[(isBus ? 0 : 128) + 64 + tid], sst[64 + tid]);
    }
  }
}

// ---------------- MFMA readout: out = x@Wro + b ----------------
__global__ void __launch_bounds__(256) k_readout(const float* __restrict__ x,
                                                 const u16* __restrict__ rot,
                                                 const float* __restrict__ robb,
                                                 const float* __restrict__ robg,
                                                 float* __restrict__ out) {
  const int tile = blockIdx.x;
  const bool isBus = tile < NTILE_BUS;
  const int tid = threadIdx.x, lane = tid & 63, wv = tid >> 6;
  const int m = lane & 15, kq = lane >> 4;
  const int arow = tile * 64 + wv * 16 + m;
  const float* xp = &x[(size_t)arow * 64 + kq * 8];
  s16x8 a0, a1;
#pragma unroll
  for (int j = 0; j < 8; j++) a0[j] = (short)f2bf(xp[j]);
#pragma unroll
  for (int j = 0; j < 8; j++) a1[j] = (short)f2bf(xp[32 + j]);
  const u16* rbase = rot + (size_t)(isBus ? 0 : 1) * 2048;
  f32x4 acc[2];
  acc[0] = (f32x4){0.f, 0.f, 0.f, 0.f};
  acc[1] = (f32x4){0.f, 0.f, 0.f, 0.f};
#pragma unroll
  for (int cb = 0; cb < 2; cb++) {
    const u16* wp = rbase + (cb * 16 + m) * 64 + kq * 8;
    s16x8 b0 = *(const s16x8*)&wp[0];
    s16x8 b1 = *(const s16x8*)&wp[32];
    acc[cb] = __builtin_amdgcn_mfma_f32_16x16x32_bf16(a0, b0, acc[cb], 0, 0, 0);
    acc[cb] = __builtin_amdgcn_mfma_f32_16x16x32_bf16(a1, b1, acc[cb], 0, 0, 0);
  }
  const float* bb = isBus ? robb : robg;
  const int orow0 = tile * 64 + wv * 16 + kq * 4;
#pragma unroll
  for (int cb = 0; cb < 2; cb++) {
    int col = cb * 16 + m;
    float bv = bb[col];
#pragma unroll
    for (int i = 0; i < 4; i++)
      out[(size_t)(orow0 + i) * 32 + col] = acc[cb][i] + bv;
  }
}

extern "C" void kernel_launch(void* const* d_in, const int* in_sizes, int n_in,
                              void* d_out, int out_size, void* d_ws, size_t ws_size,
                              hipStream_t stream) {
  const float* x_bus = (const float*)d_in[0];
  const float* x_gen = (const float*)d_in[1];
  const float* riWb = (const float*)d_in[2];
  const float* ribb = (const float*)d_in[3];
  const float* riWg = (const float*)d_in[4];
  const float* ribg = (const float*)d_in[5];
  const float* bng_b = (const float*)d_in[6];
  const float* bnb_b = (const float*)d_in[7];
  const float* bng_g = (const float*)d_in[8];
  const float* bnb_g = (const float*)d_in[9];
  const float* tWb = (const float*)d_in[10];
  const float* tbb = (const float*)d_in[11];
  const float* tWg = (const float*)d_in[12];
  const float* tbg = (const float*)d_in[13];
  const float* roWb = (const float*)d_in[14];
  const float* robb = (const float*)d_in[15];
  const float* roWg = (const float*)d_in[16];
  const float* robg = (const float*)d_in[17];
  const int* ebb = (const int*)d_in[18];
  const int* gb_src = (const int*)d_in[19];
  const int* gb_dst = (const int*)d_in[20];
  const int* bg_src = (const int*)d_in[21];
  const int* bg_dst = (const int*)d_in[22];
  const int* bb_src = ebb;
  const int* bb_dst = ebb + NEBB;

  // ---- workspace layout (256B aligned segments) ----
  char* p = (char*)d_ws;
  auto take = [&](size_t bytes) -> void* {
    void* r = (void*)p;
    p += (bytes + 255) & ~(size_t)255;
    return r;
  };
  float* x = (float*)take((size_t)NALL * 64 * 4);  // bus rows [0,NBUS), gen rows after
  u16* b0 = (u16*)take((size_t)NALL * 64 * 2);     // row-major bf16 shift-state buffers
  u16* b1 = (u16*)take((size_t)NALL * 64 * 2);
  u16* b2 = (u16*)take((size_t)NALL * 64 * 2);
  int* bus_off = (int*)take((size_t)(NBUS + 1) * 4);
  int* bus_srt = (int*)take((size_t)NEBUS * 4);
  int* bg_off = (int*)take((size_t)(NGEN + 1) * 4);
  int* bg_srt = (int*)take((size_t)NEBG * 4);
  int* bsums = (int*)take(256 * 4);
  u16* wt = (u16*)take((size_t)20 * 4096 * 2);   // bf16 [n][k] tap weights
  u16* rot = (u16*)take((size_t)2 * 2048 * 2);   // bf16 [n][k] readout weights
  u16* riwt = (u16*)take((size_t)2 * 2048 * 2);  // bf16 [n][k] readin weights
  // zero-initialized group (contiguous -> single memset)
  int* bus_cur = (int*)take((size_t)NBUS * 4);
  int* bg_cur = (int*)take((size_t)NGEN * 4);
  float* stats0 = (float*)take(256 * 4);  // [bus s, bus s2, gen s, gen s2]
  float* stats1 = (float*)take(256 * 4);
  size_t zlen = (char*)p - (char*)bus_cur;
  if ((size_t)(p - (char*)d_ws) > ws_size) return;  // ws too small -> visible validation failure

  // ---- weight prep + CSR build ----
  hipMemsetAsync(bus_cur, 0, zlen, stream);
  k_convw<<<320, 256, 0, stream>>>(tWb, tWg, roWb, roWg, riWb, riWg, wt, rot, riwt);

  k_hist_sl<<<2048, 256, 0, stream>>>(bb_dst, gb_dst, bg_dst, bus_cur, bg_cur);

  k_scan1<<<128, 256, 0, stream>>>(bus_cur, bus_off, bsums, NBUS);
  k_scan2<<<1, 256, 0, stream>>>(bsums, 128);
  k_scan3<<<512, 256, 0, stream>>>(bus_off, bus_cur, bsums, NBUS, NEBUS);

  k_scan1<<<32, 256, 0, stream>>>(bg_cur, bg_off, bsums, NGEN);
  k_scan2<<<1, 256, 0, stream>>>(bsums, 32);
  k_scan3<<<128, 256, 0, stream>>>(bg_off, bg_cur, bsums, NGEN, NEBG);

  k_fill_sl<<<2560, 256, 0, stream>>>(bb_src, bb_dst, gb_src, gb_dst, bg_src, bg_dst,
                                      bus_cur, bg_cur, bus_srt, bg_srt);

  // ---- readin (MFMA, + layer-0 BN stats) ----
  k_readin<<<NTILE, 256, 0, stream>>>(x_bus, x_gen, riwt, ribb, ribg, x, stats0);

  // ---- residual blocks: tap0 -> A,A,B2 -> A,A,B2 ----
  for (int l = 0; l < 2; l++) {
    float* statsL = (l == 0) ? stats0 : stats1;
    k_norm_tap0<<<NTILE, 256, 0, stream>>>(x, b0, statsL,
                                           bng_b + l * 64, bnb_b + l * 64,
                                           bng_g + l * 64, bnb_g + l * 64,
                                           wt, tbb, tbg, l * 5);
    k_gather<<<2560, 256, 0, stream>>>(bus_off, bus_srt, bg_off, bg_srt, b0, b1);
    k_gather<<<2560, 256, 0, stream>>>(bus_off, bus_srt, bg_off, bg_srt, b1, b2);
    k_tap2<<<NTILE, 256, 0, stream>>>(b1, b2, x, wt, tbb, tbg,
                                      l * 5 + 1, l * 5 + 2, (float*)nullptr);
    k_gather<<<2560, 256, 0, stream>>>(bus_off, bus_srt, bg_off, bg_srt, b2, b0);
    k_gather<<<2560, 256, 0, stream>>>(bus_off, bus_srt, bg_off, bg_srt, b0, b1);
    k_tap2<<<NTILE, 256, 0, stream>>>(b0, b1, x, wt, tbb, tbg,
                                      l * 5 + 3, l * 5 + 4,
                                      (l == 0) ? stats1 : (float*)nullptr);
  }

  // ---- readout ----
  k_readout<<<NTILE, 256, 0, stream>>>(x, rot, robb, robg, (float*)d_out);
}

// Round 12
// 826.615 us; speedup vs baseline: 3.5192x; 1.0154x over previous
//
#include <hip/hip_runtime.h>

#define NBUS 131072
#define NGEN 32768
#define NALL (NBUS + NGEN)
#define NEBB 2097152
#define NEGB 65536
#define NEBG 65536
#define NEBUS (NEBB + NEGB)   // merged bus-dest CSR (bb + gb)
#define NTILE (NALL / 64)     // 2560
#define NTILE_BUS (NBUS / 64) // 2048
#define NGB 2560              // gather blocks per dispatch

typedef float f32x2 __attribute__((ext_vector_type(2)));
typedef float f32x4 __attribute__((ext_vector_type(4)));
typedef short s16x8 __attribute__((ext_vector_type(8)));
typedef unsigned short u16;

__device__ inline f32x2 bf2x2(unsigned v) {
  f32x2 r;
  r.x = __builtin_bit_cast(float, v << 16);
  r.y = __builtin_bit_cast(float, v & 0xFFFF0000u);
  return r;
}
__device__ inline u16 f2bf(float f) {  // round-to-nearest-even
  unsigned u = __builtin_bit_cast(unsigned, f);
  unsigned r = u + 0x7FFFu + ((u >> 16) & 1u);
  return (u16)(r >> 16);
}
__device__ inline unsigned pack2bf(float a, float b) {
  return (unsigned)f2bf(a) | ((unsigned)f2bf(b) << 16);
}

// ---------------- weight prep (unchanged) ----------------
__global__ void __launch_bounds__(256) k_convw(const float* __restrict__ tWb,
                                               const float* __restrict__ tWg,
                                               const float* __restrict__ roWb,
                                               const float* __restrict__ roWg,
                                               const float* __restrict__ riWb,
                                               const float* __restrict__ riWg,
                                               u16* __restrict__ wt,
                                               u16* __restrict__ rot,
                                               u16* __restrict__ riwt) {
  int t = blockIdx.x * 256 + threadIdx.x;
  int S = gridDim.x * 256;
  for (int i = t; i < 20 * 4096; i += S) {
    int mat = i >> 12, off = i & 4095, n = off >> 6, k = off & 63;
    const float* src = (mat < 10) ? tWb : tWg;
    int tap = (mat < 10) ? mat : mat - 10;
    wt[i] = f2bf(src[(size_t)tap * 4096 + k * 64 + n]);
  }
  for (int i = t; i < 2 * 2048; i += S) {
    int type = i >> 11, off = i & 2047, n = off >> 6, k = off & 63;
    const float* src = type ? roWg : roWb;
    rot[i] = f2bf(src[k * 32 + n]);
  }
  for (int i = t; i < 2 * 2048; i += S) {
    int type = i >> 11, off = i & 2047, n = off >> 5, k = off & 31;
    const float* src = type ? riWg : riWb;
    riwt[i] = f2bf(src[k * 64 + n]);
  }
}

// ---------------- device: XCD-sliced hist (bid in [0,2048)) ----------------
__device__ inline void dev_hist(int bid, const int* __restrict__ bbDst,
                                const int* __restrict__ gbDst,
                                const int* __restrict__ bgDst,
                                int* __restrict__ busCnt, int* __restrict__ bgCnt) {
  const int g = bid & 7;
  const int blk = bid >> 3;
  const int start = blk * 256 + threadIdx.x;
  const int S = 256 * 256;
  int i = start;
  for (; i + 3 * S < NEBB; i += 4 * S) {
    int d0 = bbDst[i], d1 = bbDst[i + S], d2 = bbDst[i + 2 * S], d3 = bbDst[i + 3 * S];
    if ((d0 >> 14) == g) atomicAdd(&busCnt[d0], 1);
    if ((d1 >> 14) == g) atomicAdd(&busCnt[d1], 1);
    if ((d2 >> 14) == g) atomicAdd(&busCnt[d2], 1);
    if ((d3 >> 14) == g) atomicAdd(&busCnt[d3], 1);
  }
  for (; i < NEBB; i += S) {
    int d = bbDst[i];
    if ((d >> 14) == g) atomicAdd(&busCnt[d], 1);
  }
  for (i = start; i < NEGB; i += S) {
    int d = gbDst[i];
    if ((d >> 14) == g) atomicAdd(&busCnt[d], 1);
  }
  for (i = start; i < NEBG; i += S) {
    int d = bgDst[i];
    if ((d >> 12) == g) atomicAdd(&bgCnt[d], 1);
  }
}

// ---------------- device: MFMA readin (tile in [0,NTILE)) ----------------
__device__ inline void dev_readin(int tile, const float* __restrict__ xbus,
                                  const float* __restrict__ xgen,
                                  const u16* __restrict__ riwt,
                                  const float* __restrict__ bb_,
                                  const float* __restrict__ bg_,
                                  float* __restrict__ y, float* __restrict__ stats) {
  __shared__ float sst[128];
  const bool isBus = tile < NTILE_BUS;
  const int tid = threadIdx.x, lane = tid & 63, wv = tid >> 6;
  const int m = lane & 15, kq = lane >> 4;
  const int grow = tile * 64 + wv * 16 + m;
  const float* xp = isBus ? &xbus[(size_t)grow * 32] : &xgen[(size_t)(grow - NBUS) * 32];
  s16x8 a;
#pragma unroll
  for (int j = 0; j < 8; j++) a[j] = (short)f2bf(xp[kq * 8 + j]);
  const u16* rb = riwt + (size_t)(isBus ? 0 : 1) * 2048;
  const float* bb = isBus ? bb_ : bg_;
  f32x4 acc[4];
#pragma unroll
  for (int cb = 0; cb < 4; cb++) {
    acc[cb] = (f32x4){0.f, 0.f, 0.f, 0.f};
    const u16* wp = rb + (cb * 16 + m) * 32 + kq * 8;
    s16x8 b = *(const s16x8*)wp;
    acc[cb] = __builtin_amdgcn_mfma_f32_16x16x32_bf16(a, b, acc[cb], 0, 0, 0);
  }
  if (tid < 128) sst[tid] = 0.f;
  __syncthreads();
  const int orow0 = tile * 64 + wv * 16 + kq * 4;
#pragma unroll
  for (int cb = 0; cb < 4; cb++) {
    int col = cb * 16 + m;
    float bv = bb[col];
    float s1 = 0.f, s2 = 0.f;
#pragma unroll
    for (int i = 0; i < 4; i++) {
      float yo = acc[cb][i] + bv;
      y[(size_t)(orow0 + i) * 64 + col] = yo;
      s1 += yo;
      s2 = fmaf(yo, yo, s2);
    }
    atomicAdd(&sst[col], s1);
    atomicAdd(&sst[64 + col], s2);
  }
  __syncthreads();
  if (tid < 64) {
    atomicAdd(&stats[(isBus ? 0 : 128) + tid], sst[tid]);
    atomicAdd(&stats[(isBus ? 0 : 128) + 64 + tid], sst[64 + tid]);
  }
}

// ---------------- fused {hist || readin} ----------------
__global__ void __launch_bounds__(256) k_hist_readin(
    const int* __restrict__ bbDst, const int* __restrict__ gbDst,
    const int* __restrict__ bgDst, int* __restrict__ busCnt, int* __restrict__ bgCnt,
    const float* __restrict__ xbus, const float* __restrict__ xgen,
    const u16* __restrict__ riwt, const float* __restrict__ bb_,
    const float* __restrict__ bg_, float* __restrict__ y, float* __restrict__ stats) {
  if (blockIdx.x < 2048)
    dev_hist(blockIdx.x, bbDst, gbDst, bgDst, busCnt, bgCnt);
  else
    dev_readin(blockIdx.x - 2048, xbus, xgen, riwt, bb_, bg_, y, stats);
}

// ---------------- scans (bus + gen fused) ----------------
__device__ inline void dev_scan1(int bid, const int* __restrict__ in,
                                 int* __restrict__ out, int* __restrict__ bsums, int n) {
  __shared__ int sh[256];
  int t = threadIdx.x;
  int base = bid * 1024 + t * 4;
  int v0 = (base + 0 < n) ? in[base + 0] : 0;
  int v1 = (base + 1 < n) ? in[base + 1] : 0;
  int v2 = (base + 2 < n) ? in[base + 2] : 0;
  int v3 = (base + 3 < n) ? in[base + 3] : 0;
  int t0 = v0, t1 = t0 + v1, t2 = t1 + v2, t3 = t2 + v3;
  sh[t] = t3;
  __syncthreads();
  for (int off = 1; off < 256; off <<= 1) {
    int x = (t >= off) ? sh[t - off] : 0;
    __syncthreads();
    sh[t] += x;
    __syncthreads();
  }
  int excl = (t > 0) ? sh[t - 1] : 0;
  if (base + 0 < n) out[base + 0] = excl;
  if (base + 1 < n) out[base + 1] = excl + t0;
  if (base + 2 < n) out[base + 2] = excl + t1;
  if (base + 3 < n) out[base + 3] = excl + t2;
  if (t == 255) bsums[bid] = sh[255];
}

__global__ void k_scanA(const int* __restrict__ busCnt, int* __restrict__ busOff,
                        int* __restrict__ bsums, const int* __restrict__ bgCnt,
                        int* __restrict__ bgOff, int* __restrict__ bsums2) {
  if (blockIdx.x < 128)
    dev_scan1(blockIdx.x, busCnt, busOff, bsums, NBUS);
  else
    dev_scan1(blockIdx.x - 128, bgCnt, bgOff, bsums2, NGEN);
}

__device__ inline void dev_scan2(int* __restrict__ bsums, int nb) {
  __shared__ int sh[256];
  int t = threadIdx.x;
  int v = (t < nb) ? bsums[t] : 0;
  sh[t] = v;
  __syncthreads();
  for (int off = 1; off < 256; off <<= 1) {
    int x = (t >= off) ? sh[t - off] : 0;
    __syncthreads();
    sh[t] += x;
    __syncthreads();
  }
  int excl = (t > 0) ? sh[t - 1] : 0;
  if (t < nb) bsums[t] = excl;
}

__global__ void k_scanB(int* __restrict__ bsums, int* __restrict__ bsums2) {
  if (blockIdx.x == 0)
    dev_scan2(bsums, 128);
  else
    dev_scan2(bsums2, 32);
}

__device__ inline void dev_scan3(int bid, int nblk, int* __restrict__ off,
                                 int* __restrict__ cur, const int* __restrict__ bsums,
                                 int n, int E) {
  int stride = nblk * 256;
  for (int i = bid * 256 + threadIdx.x; i < n; i += stride) {
    int o = off[i] + bsums[i >> 10];
    off[i] = o;
    cur[i] = o;
  }
  if (bid == 0 && threadIdx.x == 0) off[n] = E;
}

__global__ void k_scanC(int* __restrict__ busOff, int* __restrict__ busCur,
                        const int* __restrict__ bsums, int* __restrict__ bgOff,
                        int* __restrict__ bgCur, const int* __restrict__ bsums2) {
  if (blockIdx.x < 512)
    dev_scan3(blockIdx.x, 512, busOff, busCur, bsums, NBUS, NEBUS);
  else
    dev_scan3(blockIdx.x - 512, 128, bgOff, bgCur, bsums2, NGEN, NEBG);
}

// ---------------- device: XCD-sliced fill (bid in [0,2560)) ----------------
__device__ inline void dev_fill(int bid, const int* __restrict__ bbSrc,
                                const int* __restrict__ bbDst,
                                const int* __restrict__ gbSrc,
                                const int* __restrict__ gbDst,
                                const int* __restrict__ bgSrc,
                                const int* __restrict__ bgDst,
                                int* __restrict__ busCur, int* __restrict__ bgCur,
                                int* __restrict__ busSrt, int* __restrict__ bgSrt) {
  const int g = bid & 7;
  const int tid = threadIdx.x;
  if (bid < 2048) {  // bus-bus edges
    const int blk = bid >> 3;
    const int S = 256 * 256;
    int i = blk * 256 + tid;
    for (; i + 3 * S < NEBB; i += 4 * S) {
      int d0 = bbDst[i], d1 = bbDst[i + S], d2 = bbDst[i + 2 * S], d3 = bbDst[i + 3 * S];
      if ((d0 >> 14) == g) { int p = atomicAdd(&busCur[d0], 1); busSrt[p] = bbSrc[i]; }
      if ((d1 >> 14) == g) { int p = atomicAdd(&busCur[d1], 1); busSrt[p] = bbSrc[i + S]; }
      if ((d2 >> 14) == g) { int p = atomicAdd(&busCur[d2], 1); busSrt[p] = bbSrc[i + 2 * S]; }
      if ((d3 >> 14) == g) { int p = atomicAdd(&busCur[d3], 1); busSrt[p] = bbSrc[i + 3 * S]; }
    }
    for (; i < NEBB; i += S) {
      int d = bbDst[i];
      if ((d >> 14) == g) { int p = atomicAdd(&busCur[d], 1); busSrt[p] = bbSrc[i]; }
    }
  } else if (bid < 2304) {  // gen->bus edges (src offset +NBUS)
    const int blk = (bid - 2048) >> 3;
    const int S = 32 * 256;
    for (int i = blk * 256 + tid; i < NEGB; i += S) {
      int d = gbDst[i];
      if ((d >> 14) == g) { int p = atomicAdd(&busCur[d], 1); busSrt[p] = gbSrc[i] + NBUS; }
    }
  } else {  // bus->gen edges
    const int blk = (bid - 2304) >> 3;
    const int S = 32 * 256;
    for (int i = blk * 256 + tid; i < NEBG; i += S) {
      int d = bgDst[i];
      if ((d >> 12) == g) { int p = atomicAdd(&bgCur[d], 1); bgSrt[p] = bgSrc[i]; }
    }
  }
}

// ---------------- device: BN-finalize + lrelu + MFMA tap0 (tile in [0,NTILE)) -----------
__device__ inline void dev_norm(int tile, float* __restrict__ x, u16* __restrict__ c0,
                                const float* __restrict__ stats,
                                const float* __restrict__ gammaB,
                                const float* __restrict__ betaB,
                                const float* __restrict__ gammaG,
                                const float* __restrict__ betaG,
                                const u16* __restrict__ wt,
                                const float* __restrict__ tbb,
                                const float* __restrict__ tbg, int tapIdx) {
  __shared__ u16 yt[64][72];  // padded: 2-way banks (free)
  const bool isBus = tile < NTILE_BUS;
  const int tid = threadIdx.x, lane = tid & 63, wv = tid >> 6;
  int so = isBus ? 0 : 128;
  float invN = isBus ? (1.0f / NBUS) : (1.0f / NGEN);
  float mn = stats[so + lane] * invN;
  float m2 = stats[so + 64 + lane] * invN;
  float rs = rsqrtf(m2 - mn * mn + 1e-5f);
  float scale = (isBus ? gammaB : gammaG)[lane] * rs;
  float shift = (isBus ? betaB : betaG)[lane] - mn * scale;
  unsigned* cu = (unsigned*)c0;
  int rw0 = tile * 64 + wv * 16;
  for (int i = 0; i < 16; i++) {
    int row = rw0 + i;
    float xv = x[(size_t)row * 64 + lane];
    float y = fmaf(xv, scale, shift);
    y = (y >= 0.f) ? y : 0.01f * y;
    float ypair = __shfl(y, lane ^ 1, 64);
    if ((lane & 1) == 0) {
      unsigned pk = pack2bf(y, ypair);
      cu[(size_t)row * 32 + (lane >> 1)] = pk;
      *(unsigned*)&yt[wv * 16 + i][lane] = pk;
    }
  }
  __syncthreads();
  const int m = lane & 15, kq = lane >> 4;
  const u16* wrow = wt + (size_t)((isBus ? 0 : 10) + tapIdx) * 4096;
  const float* bbase = isBus ? tbb : tbg;
  int lr = wv * 16 + m;
  s16x8 a0 = *(const s16x8*)&yt[lr][kq * 8];
  s16x8 a1 = *(const s16x8*)&yt[lr][32 + kq * 8];
  f32x4 acc[4];
#pragma unroll
  for (int cb = 0; cb < 4; cb++) acc[cb] = (f32x4){0.f, 0.f, 0.f, 0.f};
#pragma unroll
  for (int cb = 0; cb < 4; cb++) {
    const u16* wp = wrow + (cb * 16 + m) * 64 + kq * 8;
    s16x8 b0 = *(const s16x8*)&wp[0];
    s16x8 b1 = *(const s16x8*)&wp[32];
    acc[cb] = __builtin_amdgcn_mfma_f32_16x16x32_bf16(a0, b0, acc[cb], 0, 0, 0);
    acc[cb] = __builtin_amdgcn_mfma_f32_16x16x32_bf16(a1, b1, acc[cb], 0, 0, 0);
  }
  const int orow0 = tile * 64 + wv * 16 + kq * 4;
#pragma unroll
  for (int cb = 0; cb < 4; cb++) {
    int col = cb * 16 + m;
    float bsv = bbase[(size_t)tapIdx * 64 + col];
#pragma unroll
    for (int i = 0; i < 4; i++) {
      size_t idx = (size_t)(orow0 + i) * 64 + col;
      x[idx] += acc[cb][i] + bsv;
    }
  }
}

// ---------------- fused {fill || norm_tap0(l=0)} ----------------
__global__ void __launch_bounds__(256) k_fill_norm(
    const int* __restrict__ bbSrc, const int* __restrict__ bbDst,
    const int* __restrict__ gbSrc, const int* __restrict__ gbDst,
    const int* __restrict__ bgSrc, const int* __restrict__ bgDst,
    int* __restrict__ busCur, int* __restrict__ bgCur,
    int* __restrict__ busSrt, int* __restrict__ bgSrt,
    float* __restrict__ x, u16* __restrict__ c0, const float* __restrict__ stats,
    const float* __restrict__ gammaB, const float* __restrict__ betaB,
    const float* __restrict__ gammaG, const float* __restrict__ betaG,
    const u16* __restrict__ wt, const float* __restrict__ tbb,
    const float* __restrict__ tbg, int tapIdx) {
  if (blockIdx.x < 2560)
    dev_fill(blockIdx.x, bbSrc, bbDst, gbSrc, gbDst, bgSrc, bgDst,
             busCur, bgCur, busSrt, bgSrt);
  else
    dev_norm(blockIdx.x - 2560, x, c0, stats, gammaB, betaB, gammaG, betaG,
             wt, tbb, tbg, tapIdx);
}

// standalone norm (layer 1)
__global__ void __launch_bounds__(256) k_norm(
    float* __restrict__ x, u16* __restrict__ c0, const float* __restrict__ stats,
    const float* __restrict__ gammaB, const float* __restrict__ betaB,
    const float* __restrict__ gammaG, const float* __restrict__ betaG,
    const u16* __restrict__ wt, const float* __restrict__ tbb,
    const float* __restrict__ tbg, int tapIdx) {
  dev_norm(blockIdx.x, x, c0, stats, gammaB, betaB, gammaG, betaG,
           wt, tbb, tbg, tapIdx);
}

// ---------------- device: CSR gather (bid in [0,NGB)) ----------------
// 8 lanes/row, uint4 payloads; srt loaded ONCE per group (32 B coalesced) and
// broadcast via shfl -> VMEM instructions per 8-edge chunk drop 16 -> 9.
__device__ inline void dev_gather(int bid, const int* __restrict__ busOff,
                                  const int* __restrict__ busSrt,
                                  const int* __restrict__ bgOff,
                                  const int* __restrict__ bgSrt,
                                  const u16* __restrict__ src, u16* __restrict__ dst) {
  const int lane = threadIdx.x & 63;
  const int wv = threadIdx.x >> 6;
  const int grp = lane >> 3;  // row slot within wave (0..7)
  const int sub = lane & 7;   // 16 B chunk within the 128 B row
  const int gb = grp << 3;
  const unsigned* s32 = (const unsigned*)src;
  unsigned* d32 = (unsigned*)dst;
  int rowBase = (bid * 4 + wv) * 8;
  for (int row0 = rowBase; row0 < NALL; row0 += NGB * 32) {
    int row = row0 + grp;
    int beg, end;
    const int* srt;
    if (row < NBUS) {
      beg = busOff[row];
      end = busOff[row + 1];
      srt = busSrt;
    } else {
      beg = bgOff[row - NBUS];
      end = bgOff[row - NBUS + 1];
      srt = bgSrt;
    }
    f32x2 a0 = {0.f, 0.f}, a1 = {0.f, 0.f}, a2 = {0.f, 0.f}, a3 = {0.f, 0.f};
    int last = end - 1;
    for (int e = beg; e < end; e += 8) {
      int ei = e + sub;
      int sv = srt[ei <= last ? ei : last];  // one 32 B coalesced load per group
      uint4 v[8];
#pragma unroll
      for (int j = 0; j < 8; j++) {
        int s = __shfl(sv, gb + j, 64);
        uint4 vv = *(const uint4*)&s32[(size_t)s * 32 + sub * 4];
        if (e + j > last) { vv.x = 0; vv.y = 0; vv.z = 0; vv.w = 0; }
        v[j] = vv;
      }
#pragma unroll
      for (int j = 0; j < 8; j++) {
        a0 += bf2x2(v[j].x);
        a1 += bf2x2(v[j].y);
        a2 += bf2x2(v[j].z);
        a3 += bf2x2(v[j].w);
      }
    }
    uint4 o;
    o.x = pack2bf(a0.x, a0.y);
    o.y = pack2bf(a1.x, a1.y);
    o.z = pack2bf(a2.x, a2.y);
    o.w = pack2bf(a3.x, a3.y);
    *(uint4*)&d32[(size_t)row * 32 + sub * 4] = o;
  }
}

__global__ void __launch_bounds__(256) k_gather(const int* __restrict__ busOff,
                                                const int* __restrict__ busSrt,
                                                const int* __restrict__ bgOff,
                                                const int* __restrict__ bgSrt,
                                                const u16* __restrict__ src,
                                                u16* __restrict__ dst) {
  dev_gather(blockIdx.x, busOff, busSrt, bgOff, bgSrt, src, dst);
}

// ---------------- device: TWO fused MFMA tap GEMMs (tile in [0,NTILE)) ----------------
__device__ inline void dev_tap2(int tile, const u16* __restrict__ cA,
                                const u16* __restrict__ cB, float* __restrict__ x,
                                const u16* __restrict__ wt,
                                const float* __restrict__ tbb,
                                const float* __restrict__ tbg,
                                int idxA, int idxB, float* __restrict__ stats) {
  __shared__ float sst[128];
  const bool isBus = tile < NTILE_BUS;
  const int row0 = tile * 64;
  const int tid = threadIdx.x, lane = tid & 63, wv = tid >> 6;
  const int m = lane & 15, kq = lane >> 4;
  const int arow = row0 + wv * 16 + m;
  const float* bbase = isBus ? tbb : tbg;
  const u16* wbase = wt + (size_t)(isBus ? 0 : 10) * 4096;
  f32x4 acc[4];
#pragma unroll
  for (int cb = 0; cb < 4; cb++) acc[cb] = (f32x4){0.f, 0.f, 0.f, 0.f};
  const u16* cs[2] = {cA, cB};
  const int idxs[2] = {idxA, idxB};
#pragma unroll
  for (int s = 0; s < 2; s++) {
    const u16* c = cs[s];
    s16x8 a0 = *(const s16x8*)&c[(size_t)arow * 64 + kq * 8];
    s16x8 a1 = *(const s16x8*)&c[(size_t)arow * 64 + 32 + kq * 8];
    const u16* wrow = wbase + (size_t)idxs[s] * 4096;
#pragma unroll
    for (int cb = 0; cb < 4; cb++) {
      const u16* wp = wrow + (cb * 16 + m) * 64 + kq * 8;
      s16x8 b0 = *(const s16x8*)&wp[0];
      s16x8 b1 = *(const s16x8*)&wp[32];
      acc[cb] = __builtin_amdgcn_mfma_f32_16x16x32_bf16(a0, b0, acc[cb], 0, 0, 0);
      acc[cb] = __builtin_amdgcn_mfma_f32_16x16x32_bf16(a1, b1, acc[cb], 0, 0, 0);
    }
  }
  if (stats) {
    if (tid < 128) sst[tid] = 0.f;
    __syncthreads();
  }
  const int orow0 = row0 + wv * 16 + kq * 4;
#pragma unroll
  for (int cb = 0; cb < 4; cb++) {
    int col = cb * 16 + m;
    float bsv = bbase[(size_t)idxA * 64 + col] + bbase[(size_t)idxB * 64 + col];
    float s1 = 0.f, s2 = 0.f;
#pragma unroll
    for (int i = 0; i < 4; i++) {
      size_t idx = (size_t)(orow0 + i) * 64 + col;
      float xo = x[idx] + acc[cb][i] + bsv;
      x[idx] = xo;
      s1 += xo;
      s2 = fmaf(xo, xo, s2);
    }
    if (stats) {
      atomicAdd(&sst[col], s1);
      atomicAdd(&sst[64 + col], s2);
    }
  }
  if (stats) {
    __syncthreads();
    if (tid < 64) {
      atomicAdd(&stats[(isBus ? 0 : 128) + tid], sst[tid]);
      atomicAdd(&stats[(isBus ? 0 : 128) + 64 + tid], sst[64 + tid]);
    }
  }
}

__global__ void __launch_bounds__(256) k_tap2(const u16* __restrict__ cA,
                                              const u16* __restrict__ cB,
                                              float* __restrict__ x,
                                              const u16* __restrict__ wt,
                                              const float* __restrict__ tbb,
                                              const float* __restrict__ tbg,
                                              int idxA, int idxB,
                                              float* __restrict__ stats) {
  dev_tap2(blockIdx.x, cA, cB, x, wt, tbb, tbg, idxA, idxB, stats);
}

// ---------------- fused {gather(b2->b0) || tap2(b1,b2)} -- independent work -------------
__global__ void __launch_bounds__(256) k_gather_tap2(
    const int* __restrict__ busOff, const int* __restrict__ busSrt,
    const int* __restrict__ bgOff, const int* __restrict__ bgSrt,
    const u16* __restrict__ gsrc, u16* __restrict__ gdst,
    const u16* __restrict__ cA, const u16* __restrict__ cB, float* __restrict__ x,
    const u16* __restrict__ wt, const float* __restrict__ tbb,
    const float* __restrict__ tbg, int idxA, int idxB) {
  if (blockIdx.x < NGB)
    dev_gather(blockIdx.x, busOff, busSrt, bgOff, bgSrt, gsrc, gdst);
  else
    dev_tap2(blockIdx.x - NGB, cA, cB, x, wt, tbb, tbg, idxA, idxB, (float*)nullptr);
}

// ---------------- MFMA readout ----------------
__global__ void __launch_bounds__(256) k_readout(const float* __restrict__ x,
                                                 const u16* __restrict__ rot,
                                                 const float* __restrict__ robb,
                                                 const float* __restrict__ robg,
                                                 float* __restrict__ out) {
  const int tile = blockIdx.x;
  const bool isBus = tile < NTILE_BUS;
  const int tid = threadIdx.x, lane = tid & 63, wv = tid >> 6;
  const int m = lane & 15, kq = lane >> 4;
  const int arow = tile * 64 + wv * 16 + m;
  const float* xp = &x[(size_t)arow * 64 + kq * 8];
  s16x8 a0, a1;
#pragma unroll
  for (int j = 0; j < 8; j++) a0[j] = (short)f2bf(xp[j]);
#pragma unroll
  for (int j = 0; j < 8; j++) a1[j] = (short)f2bf(xp[32 + j]);
  const u16* rbase = rot + (size_t)(isBus ? 0 : 1) * 2048;
  f32x4 acc[2];
  acc[0] = (f32x4){0.f, 0.f, 0.f, 0.f};
  acc[1] = (f32x4){0.f, 0.f, 0.f, 0.f};
#pragma unroll
  for (int cb = 0; cb < 2; cb++) {
    const u16* wp = rbase + (cb * 16 + m) * 64 + kq * 8;
    s16x8 b0 = *(const s16x8*)&wp[0];
    s16x8 b1 = *(const s16x8*)&wp[32];
    acc[cb] = __builtin_amdgcn_mfma_f32_16x16x32_bf16(a0, b0, acc[cb], 0, 0, 0);
    acc[cb] = __builtin_amdgcn_mfma_f32_16x16x32_bf16(a1, b1, acc[cb], 0, 0, 0);
  }
  const float* bb = isBus ? robb : robg;
  const int orow0 = tile * 64 + wv * 16 + kq * 4;
#pragma unroll
  for (int cb = 0; cb < 2; cb++) {
    int col = cb * 16 + m;
    float bv = bb[col];
#pragma unroll
    for (int i = 0; i < 4; i++)
      out[(size_t)(orow0 + i) * 32 + col] = acc[cb][i] + bv;
  }
}

extern "C" void kernel_launch(void* const* d_in, const int* in_sizes, int n_in,
                              void* d_out, int out_size, void* d_ws, size_t ws_size,
                              hipStream_t stream) {
  const float* x_bus = (const float*)d_in[0];
  const float* x_gen = (const float*)d_in[1];
  const float* riWb = (const float*)d_in[2];
  const float* ribb = (const float*)d_in[3];
  const float* riWg = (const float*)d_in[4];
  const float* ribg = (const float*)d_in[5];
  const float* bng_b = (const float*)d_in[6];
  const float* bnb_b = (const float*)d_in[7];
  const float* bng_g = (const float*)d_in[8];
  const float* bnb_g = (const float*)d_in[9];
  const float* tWb = (const float*)d_in[10];
  const float* tbb = (const float*)d_in[11];
  const float* tWg = (const float*)d_in[12];
  const float* tbg = (const float*)d_in[13];
  const float* roWb = (const float*)d_in[14];
  const float* robb = (const float*)d_in[15];
  const float* roWg = (const float*)d_in[16];
  const float* robg = (const float*)d_in[17];
  const int* ebb = (const int*)d_in[18];
  const int* gb_src = (const int*)d_in[19];
  const int* gb_dst = (const int*)d_in[20];
  const int* bg_src = (const int*)d_in[21];
  const int* bg_dst = (const int*)d_in[22];
  const int* bb_src = ebb;
  const int* bb_dst = ebb + NEBB;

  // ---- workspace layout (256B aligned segments) ----
  char* p = (char*)d_ws;
  auto take = [&](size_t bytes) -> void* {
    void* r = (void*)p;
    p += (bytes + 255) & ~(size_t)255;
    return r;
  };
  float* x = (float*)take((size_t)NALL * 64 * 4);
  u16* b0 = (u16*)take((size_t)NALL * 64 * 2);
  u16* b1 = (u16*)take((size_t)NALL * 64 * 2);
  u16* b2 = (u16*)take((size_t)NALL * 64 * 2);
  int* bus_off = (int*)take((size_t)(NBUS + 1) * 4);
  int* bus_srt = (int*)take((size_t)NEBUS * 4);
  int* bg_off = (int*)take((size_t)(NGEN + 1) * 4);
  int* bg_srt = (int*)take((size_t)NEBG * 4);
  int* bsums = (int*)take(256 * 4);
  int* bsums2 = (int*)take(256 * 4);
  u16* wt = (u16*)take((size_t)20 * 4096 * 2);
  u16* rot = (u16*)take((size_t)2 * 2048 * 2);
  u16* riwt = (u16*)take((size_t)2 * 2048 * 2);
  // zero-initialized group (contiguous -> single memset)
  int* bus_cur = (int*)take((size_t)NBUS * 4);
  int* bg_cur = (int*)take((size_t)NGEN * 4);
  float* stats0 = (float*)take(256 * 4);
  float* stats1 = (float*)take(256 * 4);
  size_t zlen = (char*)p - (char*)bus_cur;
  if ((size_t)(p - (char*)d_ws) > ws_size) return;

  hipMemsetAsync(bus_cur, 0, zlen, stream);
  k_convw<<<320, 256, 0, stream>>>(tWb, tWg, roWb, roWg, riWb, riWg, wt, rot, riwt);

  // {hist || readin}  (readin needs riwt -> after k_convw)
  k_hist_readin<<<4608, 256, 0, stream>>>(bb_dst, gb_dst, bg_dst, bus_cur, bg_cur,
                                          x_bus, x_gen, riwt, ribb, ribg, x, stats0);

  k_scanA<<<160, 256, 0, stream>>>(bus_cur, bus_off, bsums, bg_cur, bg_off, bsums2);
  k_scanB<<<2, 256, 0, stream>>>(bsums, bsums2);
  k_scanC<<<640, 256, 0, stream>>>(bus_off, bus_cur, bsums, bg_off, bg_cur, bsums2);

  // {fill || norm_tap0 layer 0}  (norm needs stats0 from readin; fill needs scans)
  k_fill_norm<<<5120, 256, 0, stream>>>(bb_src, bb_dst, gb_src, gb_dst, bg_src, bg_dst,
                                        bus_cur, bg_cur, bus_srt, bg_srt,
                                        x, b0, stats0, bng_b, bnb_b, bng_g, bnb_g,
                                        wt, tbb, tbg, 0);

  for (int l = 0; l < 2; l++) {
    if (l == 1)
      k_norm<<<NTILE, 256, 0, stream>>>(x, b0, stats1, bng_b + 64, bnb_b + 64,
                                        bng_g + 64, bnb_g + 64, wt, tbb, tbg, 5);
    k_gather<<<NGB, 256, 0, stream>>>(bus_off, bus_srt, bg_off, bg_srt, b0, b1);
    k_gather<<<NGB, 256, 0, stream>>>(bus_off, bus_srt, bg_off, bg_srt, b1, b2);
    // {gather(b2->b0) || tap2(b1,b2)} -- disjoint buffers, tap2 writes only x
    k_gather_tap2<<<NGB + NTILE, 256, 0, stream>>>(bus_off, bus_srt, bg_off, bg_srt,
                                                   b2, b0, b1, b2, x, wt, tbb, tbg,
                                                   l * 5 + 1, l * 5 + 2);
    k_gather<<<NGB, 256, 0, stream>>>(bus_off, bus_srt, bg_off, bg_srt, b0, b1);
    k_tap2<<<NTILE, 256, 0, stream>>>(b0, b1, x, wt, tbb, tbg, l * 5 + 3, l * 5 + 4,
                                      (l == 0) ? stats1 : (float*)nullptr);
  }

  k_readout<<<NTILE, 256, 0, stream>>>(x, rot, robb, robg, (float*)d_out);
}